// Round 13
// baseline (405.180 us; speedup 1.0000x reference)
//
#include <hip/hip_runtime.h>
#include <stdint.h>
#include <stddef.h>
#include <math.h>

#define TOKS 4096
#define DM   1024
#define DIP  4384
#define DI   2048
#define CVD  2304
#define NH   32
#define HD   64
#define DST  128
#define NCH  8
#define CHK  256

typedef int v4i  __attribute__((ext_vector_type(4)));
typedef int v16i __attribute__((ext_vector_type(16)));
typedef short s8v __attribute__((ext_vector_type(8)));
typedef float f16v __attribute__((ext_vector_type(16)));
typedef unsigned short ushort_t;

// ---------------- ws layout (bytes) ----------------
static const size_t OFF_ZX    = 0;                               // float TOKS*DIP
static const size_t OFF_SX    = OFF_ZX + (size_t)TOKS*DIP*4;     // float TOKS*CVD
static const size_t OFF_ST    = OFF_SX + (size_t)TOKS*CVD*4;     // float 512*HD*DST
static const size_t OFF_YG    = OFF_ST + (size_t)512*HD*DST*4;   // float TOKS*DI
static const size_t OFF_Q1    = OFF_YG + (size_t)TOKS*DI*4;      // i8 TOKS*DM
static const size_t OFF_Q2    = OFF_Q1 + (size_t)TOKS*DM;        // i8 TOKS*DI
static const size_t OFF_WQ1   = OFF_Q2 + (size_t)TOKS*DI;        // i8 DIP*DM
static const size_t OFF_WQ2   = OFF_WQ1 + (size_t)DIP*DM;        // i8 DM*DI
static const size_t OFF_RS1   = OFF_WQ2 + (size_t)DM*DI;         // float TOKS
static const size_t OFF_RS2   = OFF_RS1 + (size_t)TOKS*4;        // float TOKS
static const size_t OFF_DT    = OFF_RS2 + (size_t)TOKS*4;        // float TOKS*NH
static const size_t OFF_ACS   = OFF_DT + (size_t)TOKS*NH*4;      // double 512*CHK
static const size_t OFF_CSUM  = OFF_ACS + (size_t)512*CHK*8;     // double 512
static const size_t OFF_PART  = OFF_CSUM + 512*8;                // double 1024
static const size_t OFF_WSC   = OFF_PART + 1024*8;               // double 2
static const size_t OFF_BH    = OFF_WSC + 64;                    // ushort TOKS*128 (frag-major)
static const size_t OFF_BL    = OFF_BH  + (size_t)TOKS*128*2;
static const size_t OFF_CHG   = OFF_BL  + (size_t)TOKS*128*2;    // ushort TOKS*128 (frag-major)
static const size_t OFF_CLG   = OFF_CHG + (size_t)TOKS*128*2;
static const size_t OFF_GRAM  = OFF_CLG + (size_t)TOKS*128*2;    // float 16*256*256 (frag-major)
static const size_t OFF_UTH   = OFF_GRAM + (size_t)16*256*256*4; // ushort 512*64*256 (frag-major)
static const size_t OFF_UTL   = OFF_UTH + (size_t)512*64*256*2;
static const size_t OFF_PH    = OFF_UTL + (size_t)512*64*256*2;  // ushort 512*64*128 (frag-major)
static const size_t OFF_PL    = OFF_PH  + (size_t)512*64*128*2;

// ---------------- bf16 split helpers ----------------
__device__ __forceinline__ ushort_t f2bf(float x) {
  union { float f; unsigned int u; } v; v.f = x;
  unsigned int r = v.u + 0x7FFFu + ((v.u >> 16) & 1u);
  return (ushort_t)(r >> 16);
}
__device__ __forceinline__ float bf2f(ushort_t h) {
  union { unsigned int u; float f; } v; v.u = ((unsigned int)h) << 16;
  return v.f;
}

// ---------------- block reduction helpers (blockDim = 256) ----------------
__device__ __forceinline__ double bsumd(double v, double* sb) {
#pragma unroll
  for (int o = 32; o; o >>= 1) v += __shfl_down(v, o);
  int lane = threadIdx.x & 63, w = threadIdx.x >> 6;
  __syncthreads();
  if (lane == 0) sb[w] = v;
  __syncthreads();
  return sb[0] + sb[1] + sb[2] + sb[3];
}
__device__ __forceinline__ double bmaxd(double v, double* sb) {
#pragma unroll
  for (int o = 32; o; o >>= 1) v = fmax(v, __shfl_down(v, o));
  int lane = threadIdx.x & 63, w = threadIdx.x >> 6;
  __syncthreads();
  if (lane == 0) sb[w] = v;
  __syncthreads();
  return fmax(fmax(sb[0], sb[1]), fmax(sb[2], sb[3]));
}
__device__ __forceinline__ void bsum3d(double& a, double& b, double& c, double* sb) {
#pragma unroll
  for (int o = 32; o; o >>= 1) {
    a += __shfl_down(a, o);
    b += __shfl_down(b, o);
    c += __shfl_down(c, o);
  }
  int lane = threadIdx.x & 63, w = threadIdx.x >> 6;
  __syncthreads();
  if (lane == 0) { sb[w * 3 + 0] = a; sb[w * 3 + 1] = b; sb[w * 3 + 2] = c; }
  __syncthreads();
  a = sb[0] + sb[3] + sb[6] + sb[9];
  b = sb[1] + sb[4] + sb[7] + sb[10];
  c = sb[2] + sb[5] + sb[8] + sb[11];
}

// ---------------- weight scale (mean |w|), fp64 ----------------
__global__ void __launch_bounds__(256) k_absmean(const float* __restrict__ w, int n, double* __restrict__ part) {
  double s = 0.0;
  for (int i = blockIdx.x * 256 + threadIdx.x; i < n; i += 512 * 256) s += (double)fabsf(w[i]);
  __shared__ double sb[4];
  s = bsumd(s, sb);
  if (threadIdx.x == 0) part[blockIdx.x] = s;
}

__global__ void __launch_bounds__(256) k_wscale(const double* __restrict__ part, double* __restrict__ wsc, int n1, int n2) {
  __shared__ double sb[4];
  double s = part[threadIdx.x] + part[threadIdx.x + 256];
  double t1 = bsumd(s, sb);
  __syncthreads();
  s = part[512 + threadIdx.x] + part[512 + threadIdx.x + 256];
  double t2 = bsumd(s, sb);
  if (threadIdx.x == 0) {
    wsc[0] = fmax(t1 / (double)n1, 1e-5);
    wsc[1] = fmax(t2 / (double)n2, 1e-5);
  }
}

__global__ void __launch_bounds__(256) k_tern(const float* __restrict__ w, int n, const double* __restrict__ wsc, int which, int8_t* __restrict__ out) {
  int i = blockIdx.x * 256 + threadIdx.x;
  if (i < n) {
    double sc = wsc[which];
    double q = fmin(fmax(rint((double)w[i] / sc), -1.0), 1.0);
    out[i] = (int8_t)q;
  }
}

// ---------------- rmsnorm + layernorm + activation quant (fp64 decisions, fused reductions) ----------------
template <int D>
__global__ void __launch_bounds__(256) k_normquant(const float* __restrict__ in, const float* __restrict__ w,
                                                   int8_t* __restrict__ q, float* __restrict__ rs) {
  constexpr int E = D / 256;
  int t = blockIdx.x, tid = threadIdx.x;
  const float* row = in + (size_t)t * D;
  __shared__ double sb[12];
  double y[E];
  double s0 = 0.0, s1 = 0.0, s2 = 0.0;
#pragma unroll
  for (int i = 0; i < E; i++) {
    double xv = (double)row[tid + 256 * i];
    double wv = (double)w[tid + 256 * i];
    s0 += xv * xv;
    double yy = wv * xv;
    y[i] = yy;
    s1 += yy;
    s2 += yy * yy;
  }
  bsum3d(s0, s1, s2, sb);
  double rr = 1.0 / sqrt(s0 / (double)D + 1e-6);
  double mu = rr * (s1 / (double)D);
  double var = rr * rr * (s2 / (double)D) - mu * mu;
  double rv = 1.0 / sqrt(var + 1e-5);
  double M = 0.0;
#pragma unroll
  for (int i = 0; i < E; i++) { y[i] = y[i] * rr - mu; M = fmax(M, fabs(y[i])); }
  M = bmaxd(M, sb);
  double am = fmax(M * rv, 1e-5);
  double sc = 127.0 / am;
#pragma unroll
  for (int i = 0; i < E; i++) {
    double qq = fmin(fmax(rint(y[i] * rv * sc), -128.0), 127.0);
    q[(size_t)t * D + tid + 256 * i] = (int8_t)qq;
  }
  if (tid == 0) rs[t] = (float)(am / 127.0);
}

// ---------------- int8 x ternary GEMM via MFMA i8 ----------------
__global__ void __launch_bounds__(256, 3) k_gemm_mfma(const int8_t* __restrict__ A, const int8_t* __restrict__ W,
                                                      const float* __restrict__ rs, const float* __restrict__ addend,
                                                      float* __restrict__ out, int M, int N, int K) {
  __shared__ int8_t Al[128 * 80];
  __shared__ int8_t Bl[128 * 80];
  int m0 = blockIdx.x * 128, n0 = blockIdx.y * 128;
  int t = threadIdx.x;
  int w = t >> 6, lane = t & 63;
  int wm = w >> 1, wn = w & 1;
  int l31 = lane & 31, lh = lane >> 5;

  v16i acc[2][2] = {};

  for (int k0 = 0; k0 < K; k0 += 64) {
    __syncthreads();
#pragma unroll
    for (int it = 0; it < 2; ++it) {
      int c = t + 256 * it;
      int row = c >> 2, kc = (c & 3) * 16;
      int4 av = *(const int4*)(A + (size_t)(m0 + row) * K + k0 + kc);
      *(int4*)(Al + row * 80 + kc) = av;
      int4 bv;
      if (n0 + row < N) bv = *(const int4*)(W + (size_t)(n0 + row) * K + k0 + kc);
      else { bv.x = bv.y = bv.z = bv.w = 0; }
      *(int4*)(Bl + row * 80 + kc) = bv;
    }
    __syncthreads();
#pragma unroll
    for (int ks = 0; ks < 2; ++ks) {
      v4i af[2], bf[2];
#pragma unroll
      for (int tm = 0; tm < 2; ++tm)
        af[tm] = *(const v4i*)(Al + (wm * 64 + tm * 32 + l31) * 80 + ks * 32 + lh * 16);
#pragma unroll
      for (int tn = 0; tn < 2; ++tn)
        bf[tn] = *(const v4i*)(Bl + (wn * 64 + tn * 32 + l31) * 80 + ks * 32 + lh * 16);
#pragma unroll
      for (int tm = 0; tm < 2; ++tm)
#pragma unroll
        for (int tn = 0; tn < 2; ++tn)
          acc[tm][tn] = __builtin_amdgcn_mfma_i32_32x32x32_i8(af[tm], bf[tn], acc[tm][tn], 0, 0, 0);
    }
  }

#pragma unroll
  for (int tm = 0; tm < 2; ++tm)
#pragma unroll
    for (int tn = 0; tn < 2; ++tn) {
      int n = n0 + wn * 64 + tn * 32 + l31;
      if (n < N) {
#pragma unroll
        for (int r = 0; r < 16; ++r) {
          int mrel = (r & 3) + 8 * (r >> 2) + 4 * lh;
          int m = m0 + wm * 64 + tm * 32 + mrel;
          float v = rs[m] * (float)acc[tm][tn][r];
          if (addend) v += addend[(size_t)m * N + n];
          out[(size_t)m * N + n] = v;
        }
      }
    }
}

// ---------------- depthwise causal conv(4) + SiLU, fused frag-major B/C bf16 split ----------------
__global__ void __launch_bounds__(256) k_conv(const float* __restrict__ zx, const float* __restrict__ cw,
                                              const float* __restrict__ cb, float* __restrict__ sx,
                                              ushort_t* __restrict__ bh2, ushort_t* __restrict__ bl2,
                                              ushort_t* __restrict__ ch2, ushort_t* __restrict__ cl2) {
  int c = blockIdx.x * 256 + threadIdx.x;
  int t = blockIdx.y;
  int b = t >> 11, l = t & 2047;
  float acc = cb[c];
#pragma unroll
  for (int k = 0; k < 4; k++) {
    int li = l - 3 + k;
    if (li >= 0) acc = fmaf(zx[(size_t)(b * 2048 + li) * DIP + DI + c], cw[c * 4 + k], acc);
  }
  float val = acc / (1.f + expf(-acc));
  sx[(size_t)t * CVD + c] = val;
  if (c >= DI) {
    int idx = c - DI;     // 0..255
    ushort_t hh = f2bf(val);
    ushort_t ll = f2bf(val - bf2f(hh));
    int bc = t >> 8, lt = (t >> 5) & 7, l31 = t & 31;
    int n = idx & 127;
    int ks = n >> 4, lhf = (n >> 3) & 1, j = n & 7;
    size_t o = ((((size_t)(bc * 8 + lt) * 8 + ks) * 2 + lhf) * 32 + l31) * 8 + j;
    if (idx < 128) { bh2[o] = hh; bl2[o] = ll; }
    else           { ch2[o] = hh; cl2[o] = ll; }
  }
}

// ---------------- dt + per-(b,c,h) cumsum of a = dt * (-exp(A_log)), in fp64 ----------------
__global__ void __launch_bounds__(256) k_cumsum(const float* __restrict__ zx, const float* __restrict__ dt_bias,
                                                const float* __restrict__ A_log, float* __restrict__ dtv,
                                                double* __restrict__ acs, double* __restrict__ csum) {
  int bid = blockIdx.x;
  int h = bid & 31, bc = bid >> 5;
  int s = threadIdx.x;
  int tok = bc * 256 + s;
  float x = zx[(size_t)tok * DIP + (DI + CVD) + h] + dt_bias[h];
  float dt = fmaxf(x, 0.f) + log1pf(expf(-fabsf(x)));
  dtv[(size_t)tok * 32 + h] = dt;
  double negA = -exp((double)A_log[h]);
  double a = (double)dt * negA;
  __shared__ double buf[256];
  buf[s] = a;
  __syncthreads();
  for (int o = 1; o < 256; o <<= 1) {
    double add = (s >= o) ? buf[s - o] : 0.0;
    __syncthreads();
    buf[s] += add;
    __syncthreads();
  }
  acs[(size_t)bid * 256 + s] = buf[s];
  if (s == 255) csum[bid] = buf[s];
}

// ---------------- Gram (frag-major in & out) ----------------
__global__ void __launch_bounds__(256) k_gram(const ushort_t* __restrict__ bh2, const ushort_t* __restrict__ bl2,
                                              const ushort_t* __restrict__ ch2, const ushort_t* __restrict__ cl2,
                                              float* __restrict__ gr2) {
  int blk = blockIdx.x;          // bc*8 + lt
  int bc = blk >> 3, lt = blk & 7;
  int t = threadIdx.x;
  int w = t >> 6, lane = t & 63;
  int l31 = lane & 31, lhf = lane >> 5;
  __shared__ float Gl[4][32 * 36];

  s8v ch[8], cl[8];
#pragma unroll
  for (int ks = 0; ks < 8; ++ks) {
    size_t ca = ((((size_t)(bc * 8 + lt) * 8 + ks) * 2 + lhf) * 32 + l31) * 8;
    ch[ks] = *(const s8v*)(ch2 + ca);
    cl[ks] = *(const s8v*)(cl2 + ca);
  }
  for (int st = w; st <= lt; st += 4) {
    f16v acc = {};
#pragma unroll
    for (int ks = 0; ks < 8; ++ks) {
      size_t ba = ((((size_t)(bc * 8 + st) * 8 + ks) * 2 + lhf) * 32 + l31) * 8;
      s8v bh = *(const s8v*)(bh2 + ba);
      s8v bl = *(const s8v*)(bl2 + ba);
      acc = __builtin_amdgcn_mfma_f32_32x32x16_bf16(ch[ks], bh, acc, 0, 0, 0);
      acc = __builtin_amdgcn_mfma_f32_32x32x16_bf16(ch[ks], bl, acc, 0, 0, 0);
      acc = __builtin_amdgcn_mfma_f32_32x32x16_bf16(cl[ks], bh, acc, 0, 0, 0);
    }
#pragma unroll
    for (int rr = 0; rr < 16; ++rr) {
      int lrow = (rr & 3) + 8 * (rr >> 2) + 4 * lhf;
      Gl[w][lrow * 36 + l31] = acc[rr];
    }
#pragma unroll
    for (int i2 = 0; i2 < 2; ++i2) {
      int idx = i2 * 2 + lhf;
      int k2g = idx >> 1, lhf2 = idx & 1;
      size_t gb = ((((size_t)(bc * 8 + lt) * 8 + st) * 2 + k2g) * 2 + lhf2) * 256 + l31 * 8;
      float4 a = *(const float4*)(&Gl[w][l31 * 36 + k2g * 16 + lhf2 * 8]);
      float4 b = *(const float4*)(&Gl[w][l31 * 36 + k2g * 16 + lhf2 * 8 + 4]);
      *(float4*)(gr2 + gb) = a;
      *(float4*)(gr2 + gb + 4) = b;
    }
  }
}

// ---------------- uT precompute (frag-major out) ----------------
__global__ void __launch_bounds__(256) k_prepuT(const float* __restrict__ sx, const float* __restrict__ dtv,
                                                ushort_t* __restrict__ uth2, ushort_t* __restrict__ utl2) {
  int r = blockIdx.x;           // (b*8+c)*32+h
  int h = r & 31, bc = r >> 5;
  int t = threadIdx.x;
  __shared__ float Xs[64 * 68];
  __shared__ float dts[64];
  for (int slab = 0; slab < 4; ++slab) {
    int s0 = slab * 64;
    if (slab) __syncthreads();
    if (t < 64) dts[t] = dtv[(size_t)(bc * 256 + s0 + t) * 32 + h];
    {
      int s = t >> 2, pg = (t & 3) * 16;
      const float* xr = sx + (size_t)(bc * 256 + s0 + s) * CVD + h * 64 + pg;
      float* dst = &Xs[s * 68 + pg];
#pragma unroll
      for (int i = 0; i < 4; ++i)
        *(float4*)(dst + i * 4) = *(const float4*)(xr + i * 4);
    }
    __syncthreads();
#pragma unroll
    for (int half = 0; half < 2; ++half) {
      int it = t + half * 256;
      int l31 = it & 31, g = it >> 5;    // g 0..15
      int stl = g >> 3, k2 = (g >> 2) & 1, pt = (g >> 1) & 1, lhf = g & 1;
      int p = pt * 32 + l31;
      int sb = stl * 32 + k2 * 16 + lhf * 8;   // within slab
      union { int4 q; ushort_t e[8]; } H, L;
#pragma unroll
      for (int j = 0; j < 8; ++j) {
        float f = Xs[(sb + j) * 68 + p] * dts[sb + j];
        ushort_t hh = f2bf(f);
        H.e[j] = hh;
        L.e[j] = f2bf(f - bf2f(hh));
      }
      int st = slab * 2 + stl;
      size_t base = (((((size_t)r * 8 + st) * 2 + k2) * 2 + pt) * 2 + lhf) * 256 + l31 * 8;
      *(int4*)(uth2 + base) = H.q;
      *(int4*)(utl2 + base) = L.q;
    }
  }
}

// ---------------- per-chunk states: states[p][n] = sum_s du[s,p]*B[s,n] ----------------
__global__ void __launch_bounds__(256, 4) k_states2(const float* __restrict__ sx, const float* __restrict__ dtv,
                                                    const double* __restrict__ acs, const double* __restrict__ csum,
                                                    float* __restrict__ states) {
  int r = blockIdx.x;
  int h = r & 31, bc = r >> 5;
  int t = threadIdx.x, tx = t & 15, ty = t >> 4;
  __shared__ float du[64 * 68];
  double last = csum[r];
  float acc[4][8] = {};
  for (int s0 = 0; s0 < 256; s0 += 64) {
    __syncthreads();
    {
      int s = t >> 2, pg = (t & 3) * 16;
      int tok = bc * 256 + s0 + s;
      float w = expf((float)(last - acs[(size_t)r * 256 + s0 + s])) * dtv[(size_t)tok * 32 + h];
      const float* xr = sx + (size_t)tok * CVD + h * 64 + pg;
      float* dst = &du[s * 68 + pg];
#pragma unroll
      for (int i = 0; i < 4; i++) {
        float4 v = *(const float4*)(xr + i * 4);
        v.x *= w; v.y *= w; v.z *= w; v.w *= w;
        *(float4*)(dst + i * 4) = v;
      }
    }
    __syncthreads();
#pragma unroll 4
    for (int s = 0; s < 64; s++) {
      int tok = bc * 256 + s0 + s;
      const float* br = sx + (size_t)tok * CVD + DI + ty * 8;
      float4 b0 = *(const float4*)(br);
      float4 b1 = *(const float4*)(br + 4);
      float4 d4 = *(const float4*)(&du[s * 68 + tx * 4]);
      float dd[4] = {d4.x, d4.y, d4.z, d4.w};
      float bv[8] = {b0.x, b0.y, b0.z, b0.w, b1.x, b1.y, b1.z, b1.w};
#pragma unroll
      for (int i = 0; i < 4; i++)
#pragma unroll
        for (int j = 0; j < 8; j++) acc[i][j] = fmaf(dd[i], bv[j], acc[i][j]);
    }
  }
  size_t base = (size_t)r * (HD * DST);
#pragma unroll
  for (int i = 0; i < 4; i++) {
    float4 v0, v1;
    v0.x = acc[i][0]; v0.y = acc[i][1]; v0.z = acc[i][2]; v0.w = acc[i][3];
    v1.x = acc[i][4]; v1.y = acc[i][5]; v1.z = acc[i][6]; v1.w = acc[i][7];
    *(float4*)(states + base + (size_t)(tx * 4 + i) * DST + ty * 8) = v0;
    *(float4*)(states + base + (size_t)(tx * 4 + i) * DST + ty * 8 + 4) = v1;
  }
}

// ---------------- chunk-state recurrence; emits prev as frag-major bf16 hi/lo ----------------
__global__ void __launch_bounds__(256) k_chunkscan(float* __restrict__ states, const double* __restrict__ csum,
                                                   ushort_t* __restrict__ ph2, ushort_t* __restrict__ pl2) {
  int idx = blockIdx.x * 256 + threadIdx.x;
  int n = idx & 127, p = (idx >> 7) & 63, h = (idx >> 13) & 31, b = idx >> 18;
  int ks = n >> 4, lhf = (n >> 3) & 1, j = n & 7, pt = p >> 5, l31 = p & 31;
  float Nv = 0.f;
  for (int c = 0; c < 8; c++) {
    int bid = (b * 8 + c) * 32 + h;
    size_t addr = (size_t)bid * (HD * DST) + p * DST + n;
    float s = states[addr];
    states[addr] = Nv;
    ushort_t hh = f2bf(Nv);
    size_t o = (((((size_t)bid * 8 + ks) * 2 + pt) * 2 + lhf) * 32 + l31) * 8 + j;
    ph2[o] = hh;
    pl2[o] = f2bf(Nv - bf2f(hh));
    Nv = Nv * expf((float)csum[bid]) + s;
  }
}

// ---------------- fused Y: balanced paired l-tiles, 2 independent waves (pt) per block ----------------
// grid = 2048 blocks x 128 thr: block = (r, pair); wave = pt; wave runs lt=pair then lt=7-pair.
__global__ void __launch_bounds__(128) k_y10(const float* __restrict__ sx, const double* __restrict__ acs,
                                             const ushort_t* __restrict__ ch2, const ushort_t* __restrict__ cl2,
                                             const ushort_t* __restrict__ ph2, const ushort_t* __restrict__ pl2,
                                             const float* __restrict__ gr2,
                                             const ushort_t* __restrict__ uth2, const ushort_t* __restrict__ utl2,
                                             const float* __restrict__ zx, const float* __restrict__ Dp,
                                             float* __restrict__ yg) {
  // bijective XCD swizzle over 2048 blocks (2048 = 8 * 256)
  int myid = (blockIdx.x & 7) * 256 + (blockIdx.x >> 3);
  int r = myid >> 2, pair = myid & 3;    // r = (b*8+c)*32+h
  int h = r & 31, bc = r >> 5;
  int pt = threadIdx.x >> 6;             // wave id = pt
  int lane = threadIdx.x & 63;
  int l31 = lane & 31, lhf = lane >> 5;
  const double* acsr = acs + (size_t)r * 256;
  float dph = Dp[h];

#pragma unroll
  for (int sel = 0; sel < 2; ++sel) {
    int lt = sel ? (7 - pair) : pair;
    int lw = lt * 32;
    int lg = lw + l31;
    double a_l = acsr[lg];

    // ---- Y_off: Yacc = C · prev^T (this pt half only) ----
    f16v Yacc = {};
#pragma unroll
    for (int ks = 0; ks < 8; ++ks) {
      size_t ca = ((((size_t)(bc * 8 + lt) * 8 + ks) * 2 + lhf) * 32 + l31) * 8;
      s8v ch = *(const s8v*)(ch2 + ca);
      s8v cl = *(const s8v*)(cl2 + ca);
      size_t pa = (((((size_t)r * 8 + ks) * 2 + pt) * 2 + lhf) * 32 + l31) * 8;
      s8v ph = *(const s8v*)(ph2 + pa);
      s8v pl = *(const s8v*)(pl2 + pa);
      Yacc = __builtin_amdgcn_mfma_f32_32x32x16_bf16(ch, ph, Yacc, 0, 0, 0);
      Yacc = __builtin_amdgcn_mfma_f32_32x32x16_bf16(ch, pl, Yacc, 0, 0, 0);
      Yacc = __builtin_amdgcn_mfma_f32_32x32x16_bf16(cl, ph, Yacc, 0, 0, 0);
    }
#pragma unroll
    for (int rr = 0; rr < 16; ++rr) {
      int lrow = (rr & 3) + 8 * (rr >> 2) + 4 * lhf;
      Yacc[rr] *= expf((float)acsr[lw + lrow]);
    }

    // ---- main loop over 32-wide s subtiles ----
    for (int st = 0; st <= lt; ++st) {
#pragma unroll
      for (int k2 = 0; k2 < 2; ++k2) {
        size_t gb = (((((size_t)(bc * 8 + lt) * 8 + st) * 2 + k2) * 2 + lhf) * 256) + l31 * 8;
        float4 g0 = *(const float4*)(gr2 + gb);
        float4 g1 = *(const float4*)(gr2 + gb + 4);
        float gv[8] = {g0.x, g0.y, g0.z, g0.w, g1.x, g1.y, g1.z, g1.w};
        int sbase = st * 32 + k2 * 16 + lhf * 8;
        union { s8v v; ushort_t e[8]; } AH, AL;
#pragma unroll
        for (int j = 0; j < 8; ++j) {
          float v = 0.f;
          if (sbase + j <= lg) v = expf((float)(a_l - acsr[sbase + j])) * gv[j];
          ushort_t hh = f2bf(v);
          AH.e[j] = hh;
          AL.e[j] = f2bf(v - bf2f(hh));
        }
        size_t ub = ((((((size_t)r * 8 + st) * 2 + k2) * 2 + pt) * 2 + lhf) * 256) + l31 * 8;
        s8v uh = *(const s8v*)(uth2 + ub);
        s8v ul = *(const s8v*)(utl2 + ub);
        Yacc = __builtin_amdgcn_mfma_f32_32x32x16_bf16(AH.v, uh, Yacc, 0, 0, 0);
        Yacc = __builtin_amdgcn_mfma_f32_32x32x16_bf16(AH.v, ul, Yacc, 0, 0, 0);
        Yacc = __builtin_amdgcn_mfma_f32_32x32x16_bf16(AL.v, uh, Yacc, 0, 0, 0);
      }
    }

    // ---- epilogue: + x*Dp, gate silu(z), store (this pt half) ----
    int p = pt * 32 + l31;
#pragma unroll
    for (int rr = 0; rr < 16; ++rr) {
      int lrow = (rr & 3) + 8 * (rr >> 2) + 4 * lhf;
      size_t tok = (size_t)(bc * 256 + lw + lrow);
      float xv = sx[tok * CVD + h * 64 + p];
      float zv = zx[tok * DIP + h * 64 + p];
      float y = (Yacc[rr] + xv * dph) * (zv / (1.f + expf(-zv)));
      yg[tok * DI + h * 64 + p] = y;
    }
  }
}

// ---------------- launch ----------------
extern "C" void kernel_launch(void* const* d_in, const int* in_sizes, int n_in,
                              void* d_out, int out_size, void* d_ws, size_t ws_size,
                              hipStream_t stream) {
  const float* hidden   = (const float*)d_in[0];
  const float* norm_w   = (const float*)d_in[1];
  const float* in_proj  = (const float*)d_in[2];
  const float* conv_w   = (const float*)d_in[3];
  const float* conv_b   = (const float*)d_in[4];
  const float* A_log    = (const float*)d_in[5];
  const float* Dp       = (const float*)d_in[6];
  const float* dt_bias  = (const float*)d_in[7];
  const float* out_norm = (const float*)d_in[8];
  const float* out_proj = (const float*)d_in[9];
  float* out = (float*)d_out;

  char* ws = (char*)d_ws;
  float*  zx    = (float*)(ws + OFF_ZX);
  float*  sx    = (float*)(ws + OFF_SX);
  float*  st    = (float*)(ws + OFF_ST);
  float*  yg    = (float*)(ws + OFF_YG);
  int8_t* q1    = (int8_t*)(ws + OFF_Q1);
  int8_t* q2    = (int8_t*)(ws + OFF_Q2);
  int8_t* wq1   = (int8_t*)(ws + OFF_WQ1);
  int8_t* wq2   = (int8_t*)(ws + OFF_WQ2);
  float*  rs1   = (float*)(ws + OFF_RS1);
  float*  rs2   = (float*)(ws + OFF_RS2);
  float*  dtv   = (float*)(ws + OFF_DT);
  double* acs   = (double*)(ws + OFF_ACS);
  double* csum  = (double*)(ws + OFF_CSUM);
  double* part  = (double*)(ws + OFF_PART);
  double* wsc   = (double*)(ws + OFF_WSC);
  ushort_t* bh2 = (ushort_t*)(ws + OFF_BH);
  ushort_t* bl2 = (ushort_t*)(ws + OFF_BL);
  ushort_t* ch2 = (ushort_t*)(ws + OFF_CHG);
  ushort_t* cl2 = (ushort_t*)(ws + OFF_CLG);
  float*  gr2   = (float*)(ws + OFF_GRAM);
  ushort_t* uth2 = (ushort_t*)(ws + OFF_UTH);
  ushort_t* utl2 = (ushort_t*)(ws + OFF_UTL);
  ushort_t* ph2 = (ushort_t*)(ws + OFF_PH);
  ushort_t* pl2 = (ushort_t*)(ws + OFF_PL);

  const int n1 = DIP * DM, n2 = DM * DI;

  hipLaunchKernelGGL(k_absmean, dim3(512), dim3(256), 0, stream, in_proj, n1, part);
  hipLaunchKernelGGL(k_absmean, dim3(512), dim3(256), 0, stream, out_proj, n2, part + 512);
  hipLaunchKernelGGL(k_wscale, dim3(1), dim3(256), 0, stream, part, wsc, n1, n2);
  hipLaunchKernelGGL(k_tern, dim3((n1 + 255) / 256), dim3(256), 0, stream, in_proj, n1, wsc, 0, wq1);
  hipLaunchKernelGGL(k_tern, dim3((n2 + 255) / 256), dim3(256), 0, stream, out_proj, n2, wsc, 1, wq2);
  hipLaunchKernelGGL(k_normquant<DM>, dim3(TOKS), dim3(256), 0, stream, hidden, norm_w, q1, rs1);
  hipLaunchKernelGGL(k_gemm_mfma, dim3(TOKS / 128, (DIP + 127) / 128), dim3(256), 0, stream,
                     q1, wq1, rs1, (const float*)nullptr, zx, TOKS, DIP, DM);
  hipLaunchKernelGGL(k_conv, dim3(CVD / 256, TOKS), dim3(256), 0, stream, zx, conv_w, conv_b, sx,
                     bh2, bl2, ch2, cl2);
  hipLaunchKernelGGL(k_cumsum, dim3(512), dim3(256), 0, stream, zx, dt_bias, A_log, dtv, acs, csum);
  hipLaunchKernelGGL(k_gram, dim3(128), dim3(256), 0, stream, bh2, bl2, ch2, cl2, gr2);
  hipLaunchKernelGGL(k_prepuT, dim3(512), dim3(256), 0, stream, sx, dtv, uth2, utl2);
  hipLaunchKernelGGL(k_states2, dim3(512), dim3(256), 0, stream, sx, dtv, acs, csum, st);
  hipLaunchKernelGGL(k_chunkscan, dim3(2 * NH * HD * DST / 256), dim3(256), 0, stream, st, csum, ph2, pl2);
  hipLaunchKernelGGL(k_y10, dim3(2048), dim3(128), 0, stream, sx, acs, ch2, cl2, ph2, pl2, gr2, uth2, utl2, zx, Dp, yg);
  hipLaunchKernelGGL(k_normquant<DI>, dim3(TOKS), dim3(256), 0, stream, yg, out_norm, q2, rs2);
  hipLaunchKernelGGL(k_gemm_mfma, dim3(TOKS / 128, DM / 128), dim3(256), 0, stream,
                     q2, wq2, rs2, hidden, out, TOKS, DM, DI);
  (void)in_sizes; (void)n_in; (void)out_size; (void)ws_size;
}

// Round 14
// 391.894 us; speedup vs baseline: 1.0339x; 1.0339x over previous
//
#include <hip/hip_runtime.h>
#include <stdint.h>
#include <stddef.h>
#include <math.h>

#define TOKS 4096
#define DM   1024
#define DIP  4384
#define DI   2048
#define CVD  2304
#define NH   32
#define HD   64
#define DST  128
#define NCH  8
#define CHK  256

typedef int v4i  __attribute__((ext_vector_type(4)));
typedef int v16i __attribute__((ext_vector_type(16)));
typedef short s8v __attribute__((ext_vector_type(8)));
typedef float f16v __attribute__((ext_vector_type(16)));
typedef unsigned short ushort_t;

// ---------------- ws layout (bytes) ----------------
static const size_t OFF_ZX    = 0;                               // float TOKS*DIP
static const size_t OFF_SX    = OFF_ZX + (size_t)TOKS*DIP*4;     // float TOKS*CVD
static const size_t OFF_ST    = OFF_SX + (size_t)TOKS*CVD*4;     // float 512*HD*DST
static const size_t OFF_YG    = OFF_ST + (size_t)512*HD*DST*4;   // float TOKS*DI
static const size_t OFF_Q1    = OFF_YG + (size_t)TOKS*DI*4;      // i8 TOKS*DM
static const size_t OFF_Q2    = OFF_Q1 + (size_t)TOKS*DM;        // i8 TOKS*DI
static const size_t OFF_WQ1   = OFF_Q2 + (size_t)TOKS*DI;        // i8 DIP*DM
static const size_t OFF_WQ2   = OFF_WQ1 + (size_t)DIP*DM;        // i8 DM*DI
static const size_t OFF_RS1   = OFF_WQ2 + (size_t)DM*DI;         // float TOKS
static const size_t OFF_RS2   = OFF_RS1 + (size_t)TOKS*4;        // float TOKS
static const size_t OFF_DT    = OFF_RS2 + (size_t)TOKS*4;        // float TOKS*NH
static const size_t OFF_ACS   = OFF_DT + (size_t)TOKS*NH*4;      // double 512*CHK
static const size_t OFF_CSUM  = OFF_ACS + (size_t)512*CHK*8;     // double 512
static const size_t OFF_PART  = OFF_CSUM + 512*8;                // double 1024
static const size_t OFF_WSC   = OFF_PART + 1024*8;               // double 2
static const size_t OFF_BH    = OFF_WSC + 64;                    // ushort TOKS*128 (frag-major)
static const size_t OFF_BL    = OFF_BH  + (size_t)TOKS*128*2;
static const size_t OFF_CHG   = OFF_BL  + (size_t)TOKS*128*2;    // ushort TOKS*128 (frag-major)
static const size_t OFF_CLG   = OFF_CHG + (size_t)TOKS*128*2;
static const size_t OFF_GRAM  = OFF_CLG + (size_t)TOKS*128*2;    // float 16*256*256 (frag-major)
static const size_t OFF_UTH   = OFF_GRAM + (size_t)16*256*256*4; // ushort 512*64*256 (frag-major)
static const size_t OFF_UTL   = OFF_UTH + (size_t)512*64*256*2;
static const size_t OFF_PH    = OFF_UTL + (size_t)512*64*256*2;  // ushort 512*64*128 (frag-major)
static const size_t OFF_PL    = OFF_PH  + (size_t)512*64*128*2;

// ---------------- bf16 split helpers ----------------
__device__ __forceinline__ ushort_t f2bf(float x) {
  union { float f; unsigned int u; } v; v.f = x;
  unsigned int r = v.u + 0x7FFFu + ((v.u >> 16) & 1u);
  return (ushort_t)(r >> 16);
}
__device__ __forceinline__ float bf2f(ushort_t h) {
  union { unsigned int u; float f; } v; v.u = ((unsigned int)h) << 16;
  return v.f;
}

// ---------------- block reduction helpers (blockDim = 256) ----------------
__device__ __forceinline__ double bsumd(double v, double* sb) {
#pragma unroll
  for (int o = 32; o; o >>= 1) v += __shfl_down(v, o);
  int lane = threadIdx.x & 63, w = threadIdx.x >> 6;
  __syncthreads();
  if (lane == 0) sb[w] = v;
  __syncthreads();
  return sb[0] + sb[1] + sb[2] + sb[3];
}
__device__ __forceinline__ double bmaxd(double v, double* sb) {
#pragma unroll
  for (int o = 32; o; o >>= 1) v = fmax(v, __shfl_down(v, o));
  int lane = threadIdx.x & 63, w = threadIdx.x >> 6;
  __syncthreads();
  if (lane == 0) sb[w] = v;
  __syncthreads();
  return fmax(fmax(sb[0], sb[1]), fmax(sb[2], sb[3]));
}
__device__ __forceinline__ void bsum3d(double& a, double& b, double& c, double* sb) {
#pragma unroll
  for (int o = 32; o; o >>= 1) {
    a += __shfl_down(a, o);
    b += __shfl_down(b, o);
    c += __shfl_down(c, o);
  }
  int lane = threadIdx.x & 63, w = threadIdx.x >> 6;
  __syncthreads();
  if (lane == 0) { sb[w * 3 + 0] = a; sb[w * 3 + 1] = b; sb[w * 3 + 2] = c; }
  __syncthreads();
  a = sb[0] + sb[3] + sb[6] + sb[9];
  b = sb[1] + sb[4] + sb[7] + sb[10];
  c = sb[2] + sb[5] + sb[8] + sb[11];
}

// ---------------- weight scale (mean |w|), fp64 ----------------
__global__ void __launch_bounds__(256) k_absmean(const float* __restrict__ w, int n, double* __restrict__ part) {
  double s = 0.0;
  for (int i = blockIdx.x * 256 + threadIdx.x; i < n; i += 512 * 256) s += (double)fabsf(w[i]);
  __shared__ double sb[4];
  s = bsumd(s, sb);
  if (threadIdx.x == 0) part[blockIdx.x] = s;
}

__global__ void __launch_bounds__(256) k_wscale(const double* __restrict__ part, double* __restrict__ wsc, int n1, int n2) {
  __shared__ double sb[4];
  double s = part[threadIdx.x] + part[threadIdx.x + 256];
  double t1 = bsumd(s, sb);
  __syncthreads();
  s = part[512 + threadIdx.x] + part[512 + threadIdx.x + 256];
  double t2 = bsumd(s, sb);
  if (threadIdx.x == 0) {
    wsc[0] = fmax(t1 / (double)n1, 1e-5);
    wsc[1] = fmax(t2 / (double)n2, 1e-5);
  }
}

__global__ void __launch_bounds__(256) k_tern(const float* __restrict__ w, int n, const double* __restrict__ wsc, int which, int8_t* __restrict__ out) {
  int i = blockIdx.x * 256 + threadIdx.x;
  if (i < n) {
    double sc = wsc[which];
    double q = fmin(fmax(rint((double)w[i] / sc), -1.0), 1.0);
    out[i] = (int8_t)q;
  }
}

// ---------------- rmsnorm + layernorm + activation quant (fp64 decisions, fused reductions) ----------------
template <int D>
__global__ void __launch_bounds__(256) k_normquant(const float* __restrict__ in, const float* __restrict__ w,
                                                   int8_t* __restrict__ q, float* __restrict__ rs) {
  constexpr int E = D / 256;
  int t = blockIdx.x, tid = threadIdx.x;
  const float* row = in + (size_t)t * D;
  __shared__ double sb[12];
  double y[E];
  double s0 = 0.0, s1 = 0.0, s2 = 0.0;
#pragma unroll
  for (int i = 0; i < E; i++) {
    double xv = (double)row[tid + 256 * i];
    double wv = (double)w[tid + 256 * i];
    s0 += xv * xv;
    double yy = wv * xv;
    y[i] = yy;
    s1 += yy;
    s2 += yy * yy;
  }
  bsum3d(s0, s1, s2, sb);
  double rr = 1.0 / sqrt(s0 / (double)D + 1e-6);
  double mu = rr * (s1 / (double)D);
  double var = rr * rr * (s2 / (double)D) - mu * mu;
  double rv = 1.0 / sqrt(var + 1e-5);
  double M = 0.0;
#pragma unroll
  for (int i = 0; i < E; i++) { y[i] = y[i] * rr - mu; M = fmax(M, fabs(y[i])); }
  M = bmaxd(M, sb);
  double am = fmax(M * rv, 1e-5);
  double sc = 127.0 / am;
#pragma unroll
  for (int i = 0; i < E; i++) {
    double qq = fmin(fmax(rint(y[i] * rv * sc), -128.0), 127.0);
    q[(size_t)t * D + tid + 256 * i] = (int8_t)qq;
  }
  if (tid == 0) rs[t] = (float)(am / 127.0);
}

// ---------------- int8 x ternary GEMM via MFMA i8 ----------------
__global__ void __launch_bounds__(256, 3) k_gemm_mfma(const int8_t* __restrict__ A, const int8_t* __restrict__ W,
                                                      const float* __restrict__ rs, const float* __restrict__ addend,
                                                      float* __restrict__ out, int M, int N, int K) {
  __shared__ int8_t Al[128 * 80];
  __shared__ int8_t Bl[128 * 80];
  int m0 = blockIdx.x * 128, n0 = blockIdx.y * 128;
  int t = threadIdx.x;
  int w = t >> 6, lane = t & 63;
  int wm = w >> 1, wn = w & 1;
  int l31 = lane & 31, lh = lane >> 5;

  v16i acc[2][2] = {};

  for (int k0 = 0; k0 < K; k0 += 64) {
    __syncthreads();
#pragma unroll
    for (int it = 0; it < 2; ++it) {
      int c = t + 256 * it;
      int row = c >> 2, kc = (c & 3) * 16;
      int4 av = *(const int4*)(A + (size_t)(m0 + row) * K + k0 + kc);
      *(int4*)(Al + row * 80 + kc) = av;
      int4 bv;
      if (n0 + row < N) bv = *(const int4*)(W + (size_t)(n0 + row) * K + k0 + kc);
      else { bv.x = bv.y = bv.z = bv.w = 0; }
      *(int4*)(Bl + row * 80 + kc) = bv;
    }
    __syncthreads();
#pragma unroll
    for (int ks = 0; ks < 2; ++ks) {
      v4i af[2], bf[2];
#pragma unroll
      for (int tm = 0; tm < 2; ++tm)
        af[tm] = *(const v4i*)(Al + (wm * 64 + tm * 32 + l31) * 80 + ks * 32 + lh * 16);
#pragma unroll
      for (int tn = 0; tn < 2; ++tn)
        bf[tn] = *(const v4i*)(Bl + (wn * 64 + tn * 32 + l31) * 80 + ks * 32 + lh * 16);
#pragma unroll
      for (int tm = 0; tm < 2; ++tm)
#pragma unroll
        for (int tn = 0; tn < 2; ++tn)
          acc[tm][tn] = __builtin_amdgcn_mfma_i32_32x32x32_i8(af[tm], bf[tn], acc[tm][tn], 0, 0, 0);
    }
  }

#pragma unroll
  for (int tm = 0; tm < 2; ++tm)
#pragma unroll
    for (int tn = 0; tn < 2; ++tn) {
      int n = n0 + wn * 64 + tn * 32 + l31;
      if (n < N) {
#pragma unroll
        for (int r = 0; r < 16; ++r) {
          int mrel = (r & 3) + 8 * (r >> 2) + 4 * lh;
          int m = m0 + wm * 64 + tm * 32 + mrel;
          float v = rs[m] * (float)acc[tm][tn][r];
          if (addend) v += addend[(size_t)m * N + n];
          out[(size_t)m * N + n] = v;
        }
      }
    }
}

// ---------------- depthwise causal conv(4) + SiLU, fused frag-major B/C bf16 split ----------------
__global__ void __launch_bounds__(256) k_conv(const float* __restrict__ zx, const float* __restrict__ cw,
                                              const float* __restrict__ cb, float* __restrict__ sx,
                                              ushort_t* __restrict__ bh2, ushort_t* __restrict__ bl2,
                                              ushort_t* __restrict__ ch2, ushort_t* __restrict__ cl2) {
  int c = blockIdx.x * 256 + threadIdx.x;
  int t = blockIdx.y;
  int b = t >> 11, l = t & 2047;
  float acc = cb[c];
#pragma unroll
  for (int k = 0; k < 4; k++) {
    int li = l - 3 + k;
    if (li >= 0) acc = fmaf(zx[(size_t)(b * 2048 + li) * DIP + DI + c], cw[c * 4 + k], acc);
  }
  float val = acc / (1.f + expf(-acc));
  sx[(size_t)t * CVD + c] = val;
  if (c >= DI) {
    int idx = c - DI;     // 0..255
    ushort_t hh = f2bf(val);
    ushort_t ll = f2bf(val - bf2f(hh));
    int bc = t >> 8, lt = (t >> 5) & 7, l31 = t & 31;
    int n = idx & 127;
    int ks = n >> 4, lhf = (n >> 3) & 1, j = n & 7;
    size_t o = ((((size_t)(bc * 8 + lt) * 8 + ks) * 2 + lhf) * 32 + l31) * 8 + j;
    if (idx < 128) { bh2[o] = hh; bl2[o] = ll; }
    else           { ch2[o] = hh; cl2[o] = ll; }
  }
}

// ---------------- dt + per-(b,c,h) cumsum of a = dt * (-exp(A_log)), in fp64 ----------------
__global__ void __launch_bounds__(256) k_cumsum(const float* __restrict__ zx, const float* __restrict__ dt_bias,
                                                const float* __restrict__ A_log, float* __restrict__ dtv,
                                                double* __restrict__ acs, double* __restrict__ csum) {
  int bid = blockIdx.x;
  int h = bid & 31, bc = bid >> 5;
  int s = threadIdx.x;
  int tok = bc * 256 + s;
  float x = zx[(size_t)tok * DIP + (DI + CVD) + h] + dt_bias[h];
  float dt = fmaxf(x, 0.f) + log1pf(expf(-fabsf(x)));
  dtv[(size_t)tok * 32 + h] = dt;
  double negA = -exp((double)A_log[h]);
  double a = (double)dt * negA;
  __shared__ double buf[256];
  buf[s] = a;
  __syncthreads();
  for (int o = 1; o < 256; o <<= 1) {
    double add = (s >= o) ? buf[s - o] : 0.0;
    __syncthreads();
    buf[s] += add;
    __syncthreads();
  }
  acs[(size_t)bid * 256 + s] = buf[s];
  if (s == 255) csum[bid] = buf[s];
}

// ---------------- Gram (frag-major in & out) ----------------
__global__ void __launch_bounds__(256) k_gram(const ushort_t* __restrict__ bh2, const ushort_t* __restrict__ bl2,
                                              const ushort_t* __restrict__ ch2, const ushort_t* __restrict__ cl2,
                                              float* __restrict__ gr2) {
  int blk = blockIdx.x;          // bc*8 + lt
  int bc = blk >> 3, lt = blk & 7;
  int t = threadIdx.x;
  int w = t >> 6, lane = t & 63;
  int l31 = lane & 31, lhf = lane >> 5;
  __shared__ float Gl[4][32 * 36];

  s8v ch[8], cl[8];
#pragma unroll
  for (int ks = 0; ks < 8; ++ks) {
    size_t ca = ((((size_t)(bc * 8 + lt) * 8 + ks) * 2 + lhf) * 32 + l31) * 8;
    ch[ks] = *(const s8v*)(ch2 + ca);
    cl[ks] = *(const s8v*)(cl2 + ca);
  }
  for (int st = w; st <= lt; st += 4) {
    f16v acc = {};
#pragma unroll
    for (int ks = 0; ks < 8; ++ks) {
      size_t ba = ((((size_t)(bc * 8 + st) * 8 + ks) * 2 + lhf) * 32 + l31) * 8;
      s8v bh = *(const s8v*)(bh2 + ba);
      s8v bl = *(const s8v*)(bl2 + ba);
      acc = __builtin_amdgcn_mfma_f32_32x32x16_bf16(ch[ks], bh, acc, 0, 0, 0);
      acc = __builtin_amdgcn_mfma_f32_32x32x16_bf16(ch[ks], bl, acc, 0, 0, 0);
      acc = __builtin_amdgcn_mfma_f32_32x32x16_bf16(cl[ks], bh, acc, 0, 0, 0);
    }
#pragma unroll
    for (int rr = 0; rr < 16; ++rr) {
      int lrow = (rr & 3) + 8 * (rr >> 2) + 4 * lhf;
      Gl[w][lrow * 36 + l31] = acc[rr];
    }
#pragma unroll
    for (int i2 = 0; i2 < 2; ++i2) {
      int idx = i2 * 2 + lhf;
      int k2g = idx >> 1, lhf2 = idx & 1;
      size_t gb = ((((size_t)(bc * 8 + lt) * 8 + st) * 2 + k2g) * 2 + lhf2) * 256 + l31 * 8;
      float4 a = *(const float4*)(&Gl[w][l31 * 36 + k2g * 16 + lhf2 * 8]);
      float4 b = *(const float4*)(&Gl[w][l31 * 36 + k2g * 16 + lhf2 * 8 + 4]);
      *(float4*)(gr2 + gb) = a;
      *(float4*)(gr2 + gb + 4) = b;
    }
  }
}

// ---------------- uT precompute (frag-major out) ----------------
__global__ void __launch_bounds__(256) k_prepuT(const float* __restrict__ sx, const float* __restrict__ dtv,
                                                ushort_t* __restrict__ uth2, ushort_t* __restrict__ utl2) {
  int r = blockIdx.x;           // (b*8+c)*32+h
  int h = r & 31, bc = r >> 5;
  int t = threadIdx.x;
  __shared__ float Xs[64 * 68];
  __shared__ float dts[64];
  for (int slab = 0; slab < 4; ++slab) {
    int s0 = slab * 64;
    if (slab) __syncthreads();
    if (t < 64) dts[t] = dtv[(size_t)(bc * 256 + s0 + t) * 32 + h];
    {
      int s = t >> 2, pg = (t & 3) * 16;
      const float* xr = sx + (size_t)(bc * 256 + s0 + s) * CVD + h * 64 + pg;
      float* dst = &Xs[s * 68 + pg];
#pragma unroll
      for (int i = 0; i < 4; ++i)
        *(float4*)(dst + i * 4) = *(const float4*)(xr + i * 4);
    }
    __syncthreads();
#pragma unroll
    for (int half = 0; half < 2; ++half) {
      int it = t + half * 256;
      int l31 = it & 31, g = it >> 5;    // g 0..15
      int stl = g >> 3, k2 = (g >> 2) & 1, pt = (g >> 1) & 1, lhf = g & 1;
      int p = pt * 32 + l31;
      int sb = stl * 32 + k2 * 16 + lhf * 8;   // within slab
      union { int4 q; ushort_t e[8]; } H, L;
#pragma unroll
      for (int j = 0; j < 8; ++j) {
        float f = Xs[(sb + j) * 68 + p] * dts[sb + j];
        ushort_t hh = f2bf(f);
        H.e[j] = hh;
        L.e[j] = f2bf(f - bf2f(hh));
      }
      int st = slab * 2 + stl;
      size_t base = (((((size_t)r * 8 + st) * 2 + k2) * 2 + pt) * 2 + lhf) * 256 + l31 * 8;
      *(int4*)(uth2 + base) = H.q;
      *(int4*)(utl2 + base) = L.q;
    }
  }
}

// ---------------- per-chunk states: states[p][n] = sum_s du[s,p]*B[s,n] ----------------
__global__ void __launch_bounds__(256, 4) k_states2(const float* __restrict__ sx, const float* __restrict__ dtv,
                                                    const double* __restrict__ acs, const double* __restrict__ csum,
                                                    float* __restrict__ states) {
  int r = blockIdx.x;
  int h = r & 31, bc = r >> 5;
  int t = threadIdx.x, tx = t & 15, ty = t >> 4;
  __shared__ float du[64 * 68];
  double last = csum[r];
  float acc[4][8] = {};
  for (int s0 = 0; s0 < 256; s0 += 64) {
    __syncthreads();
    {
      int s = t >> 2, pg = (t & 3) * 16;
      int tok = bc * 256 + s0 + s;
      float w = expf((float)(last - acs[(size_t)r * 256 + s0 + s])) * dtv[(size_t)tok * 32 + h];
      const float* xr = sx + (size_t)tok * CVD + h * 64 + pg;
      float* dst = &du[s * 68 + pg];
#pragma unroll
      for (int i = 0; i < 4; i++) {
        float4 v = *(const float4*)(xr + i * 4);
        v.x *= w; v.y *= w; v.z *= w; v.w *= w;
        *(float4*)(dst + i * 4) = v;
      }
    }
    __syncthreads();
#pragma unroll 4
    for (int s = 0; s < 64; s++) {
      int tok = bc * 256 + s0 + s;
      const float* br = sx + (size_t)tok * CVD + DI + ty * 8;
      float4 b0 = *(const float4*)(br);
      float4 b1 = *(const float4*)(br + 4);
      float4 d4 = *(const float4*)(&du[s * 68 + tx * 4]);
      float dd[4] = {d4.x, d4.y, d4.z, d4.w};
      float bv[8] = {b0.x, b0.y, b0.z, b0.w, b1.x, b1.y, b1.z, b1.w};
#pragma unroll
      for (int i = 0; i < 4; i++)
#pragma unroll
        for (int j = 0; j < 8; j++) acc[i][j] = fmaf(dd[i], bv[j], acc[i][j]);
    }
  }
  size_t base = (size_t)r * (HD * DST);
#pragma unroll
  for (int i = 0; i < 4; i++) {
    float4 v0, v1;
    v0.x = acc[i][0]; v0.y = acc[i][1]; v0.z = acc[i][2]; v0.w = acc[i][3];
    v1.x = acc[i][4]; v1.y = acc[i][5]; v1.z = acc[i][6]; v1.w = acc[i][7];
    *(float4*)(states + base + (size_t)(tx * 4 + i) * DST + ty * 8) = v0;
    *(float4*)(states + base + (size_t)(tx * 4 + i) * DST + ty * 8 + 4) = v1;
  }
}

// ---------------- chunk-state recurrence; emits prev as frag-major bf16 hi/lo ----------------
__global__ void __launch_bounds__(256) k_chunkscan(float* __restrict__ states, const double* __restrict__ csum,
                                                   ushort_t* __restrict__ ph2, ushort_t* __restrict__ pl2) {
  int idx = blockIdx.x * 256 + threadIdx.x;
  int n = idx & 127, p = (idx >> 7) & 63, h = (idx >> 13) & 31, b = idx >> 18;
  int ks = n >> 4, lhf = (n >> 3) & 1, j = n & 7, pt = p >> 5, l31 = p & 31;
  float Nv = 0.f;
  for (int c = 0; c < 8; c++) {
    int bid = (b * 8 + c) * 32 + h;
    size_t addr = (size_t)bid * (HD * DST) + p * DST + n;
    float s = states[addr];
    states[addr] = Nv;
    ushort_t hh = f2bf(Nv);
    size_t o = (((((size_t)bid * 8 + ks) * 2 + pt) * 2 + lhf) * 32 + l31) * 8 + j;
    ph2[o] = hh;
    pl2[o] = f2bf(Nv - bf2f(hh));
    Nv = Nv * expf((float)csum[bid]) + s;
  }
}

// ---------------- fused Y: 2 independent single-item waves per 128-thread block ----------------
// grid = 2048 blocks x 128 thr; item = myid*2 + waveid; item = r*8 + lt.
__global__ void __launch_bounds__(128) k_y11(const float* __restrict__ sx, const double* __restrict__ acs,
                                             const ushort_t* __restrict__ ch2, const ushort_t* __restrict__ cl2,
                                             const ushort_t* __restrict__ ph2, const ushort_t* __restrict__ pl2,
                                             const float* __restrict__ gr2,
                                             const ushort_t* __restrict__ uth2, const ushort_t* __restrict__ utl2,
                                             const float* __restrict__ zx, const float* __restrict__ Dp,
                                             float* __restrict__ yg) {
  // bijective XCD swizzle over 2048 blocks (2048 = 8 * 256)
  int myid = (blockIdx.x & 7) * 256 + (blockIdx.x >> 3);
  int item = myid * 2 + (threadIdx.x >> 6);
  int r = item >> 3, lt = item & 7;      // r = (b*8+c)*32+h
  int h = r & 31, bc = r >> 5;
  int lane = threadIdx.x & 63;
  int l31 = lane & 31, lhf = lane >> 5;
  int lw = lt * 32;
  int lg = lw + l31;
  const double* acsr = acs + (size_t)r * 256;
  double a_l = acsr[lg];

  // ---- Y_off: Yacc = C · prev^T ----
  f16v Yacc[2] = {};
#pragma unroll
  for (int ks = 0; ks < 8; ++ks) {
    size_t ca = ((((size_t)(bc * 8 + lt) * 8 + ks) * 2 + lhf) * 32 + l31) * 8;
    s8v ch = *(const s8v*)(ch2 + ca);
    s8v cl = *(const s8v*)(cl2 + ca);
#pragma unroll
    for (int pt = 0; pt < 2; ++pt) {
      size_t pa = (((((size_t)r * 8 + ks) * 2 + pt) * 2 + lhf) * 32 + l31) * 8;
      s8v ph = *(const s8v*)(ph2 + pa);
      s8v pl = *(const s8v*)(pl2 + pa);
      Yacc[pt] = __builtin_amdgcn_mfma_f32_32x32x16_bf16(ch, ph, Yacc[pt], 0, 0, 0);
      Yacc[pt] = __builtin_amdgcn_mfma_f32_32x32x16_bf16(ch, pl, Yacc[pt], 0, 0, 0);
      Yacc[pt] = __builtin_amdgcn_mfma_f32_32x32x16_bf16(cl, ph, Yacc[pt], 0, 0, 0);
    }
  }
#pragma unroll
  for (int rr = 0; rr < 16; ++rr) {
    int lrow = (rr & 3) + 8 * (rr >> 2) + 4 * lhf;
    float el = expf((float)acsr[lw + lrow]);
    Yacc[0][rr] *= el;
    Yacc[1][rr] *= el;
  }

  // ---- main loop over 32-wide s subtiles ----
  for (int st = 0; st <= lt; ++st) {
#pragma unroll
    for (int k2 = 0; k2 < 2; ++k2) {
      size_t gb = (((((size_t)(bc * 8 + lt) * 8 + st) * 2 + k2) * 2 + lhf) * 256) + l31 * 8;
      float4 g0 = *(const float4*)(gr2 + gb);
      float4 g1 = *(const float4*)(gr2 + gb + 4);
      float gv[8] = {g0.x, g0.y, g0.z, g0.w, g1.x, g1.y, g1.z, g1.w};
      int sbase = st * 32 + k2 * 16 + lhf * 8;
      union { s8v v; ushort_t e[8]; } AH, AL;
#pragma unroll
      for (int j = 0; j < 8; ++j) {
        float v = 0.f;
        if (sbase + j <= lg) v = expf((float)(a_l - acsr[sbase + j])) * gv[j];
        ushort_t hh = f2bf(v);
        AH.e[j] = hh;
        AL.e[j] = f2bf(v - bf2f(hh));
      }
#pragma unroll
      for (int pt = 0; pt < 2; ++pt) {
        size_t ub = ((((((size_t)r * 8 + st) * 2 + k2) * 2 + pt) * 2 + lhf) * 256) + l31 * 8;
        s8v uh = *(const s8v*)(uth2 + ub);
        s8v ul = *(const s8v*)(utl2 + ub);
        Yacc[pt] = __builtin_amdgcn_mfma_f32_32x32x16_bf16(AH.v, uh, Yacc[pt], 0, 0, 0);
        Yacc[pt] = __builtin_amdgcn_mfma_f32_32x32x16_bf16(AH.v, ul, Yacc[pt], 0, 0, 0);
        Yacc[pt] = __builtin_amdgcn_mfma_f32_32x32x16_bf16(AL.v, uh, Yacc[pt], 0, 0, 0);
      }
    }
  }

  // ---- epilogue: + x*Dp, gate silu(z), store ----
  float dph = Dp[h];
#pragma unroll
  for (int pt = 0; pt < 2; ++pt) {
    int p = pt * 32 + l31;
#pragma unroll
    for (int rr = 0; rr < 16; ++rr) {
      int lrow = (rr & 3) + 8 * (rr >> 2) + 4 * lhf;
      size_t tok = (size_t)(bc * 256 + lw + lrow);
      float xv = sx[tok * CVD + h * 64 + p];
      float zv = zx[tok * DIP + h * 64 + p];
      float y = (Yacc[pt][rr] + xv * dph) * (zv / (1.f + expf(-zv)));
      yg[tok * DI + h * 64 + p] = y;
    }
  }
}

// ---------------- launch ----------------
extern "C" void kernel_launch(void* const* d_in, const int* in_sizes, int n_in,
                              void* d_out, int out_size, void* d_ws, size_t ws_size,
                              hipStream_t stream) {
  const float* hidden   = (const float*)d_in[0];
  const float* norm_w   = (const float*)d_in[1];
  const float* in_proj  = (const float*)d_in[2];
  const float* conv_w   = (const float*)d_in[3];
  const float* conv_b   = (const float*)d_in[4];
  const float* A_log    = (const float*)d_in[5];
  const float* Dp       = (const float*)d_in[6];
  const float* dt_bias  = (const float*)d_in[7];
  const float* out_norm = (const float*)d_in[8];
  const float* out_proj = (const float*)d_in[9];
  float* out = (float*)d_out;

  char* ws = (char*)d_ws;
  float*  zx    = (float*)(ws + OFF_ZX);
  float*  sx    = (float*)(ws + OFF_SX);
  float*  st    = (float*)(ws + OFF_ST);
  float*  yg    = (float*)(ws + OFF_YG);
  int8_t* q1    = (int8_t*)(ws + OFF_Q1);
  int8_t* q2    = (int8_t*)(ws + OFF_Q2);
  int8_t* wq1   = (int8_t*)(ws + OFF_WQ1);
  int8_t* wq2   = (int8_t*)(ws + OFF_WQ2);
  float*  rs1   = (float*)(ws + OFF_RS1);
  float*  rs2   = (float*)(ws + OFF_RS2);
  float*  dtv   = (float*)(ws + OFF_DT);
  double* acs   = (double*)(ws + OFF_ACS);
  double* csum  = (double*)(ws + OFF_CSUM);
  double* part  = (double*)(ws + OFF_PART);
  double* wsc   = (double*)(ws + OFF_WSC);
  ushort_t* bh2 = (ushort_t*)(ws + OFF_BH);
  ushort_t* bl2 = (ushort_t*)(ws + OFF_BL);
  ushort_t* ch2 = (ushort_t*)(ws + OFF_CHG);
  ushort_t* cl2 = (ushort_t*)(ws + OFF_CLG);
  float*  gr2   = (float*)(ws + OFF_GRAM);
  ushort_t* uth2 = (ushort_t*)(ws + OFF_UTH);
  ushort_t* utl2 = (ushort_t*)(ws + OFF_UTL);
  ushort_t* ph2 = (ushort_t*)(ws + OFF_PH);
  ushort_t* pl2 = (ushort_t*)(ws + OFF_PL);

  const int n1 = DIP * DM, n2 = DM * DI;

  hipLaunchKernelGGL(k_absmean, dim3(512), dim3(256), 0, stream, in_proj, n1, part);
  hipLaunchKernelGGL(k_absmean, dim3(512), dim3(256), 0, stream, out_proj, n2, part + 512);
  hipLaunchKernelGGL(k_wscale, dim3(1), dim3(256), 0, stream, part, wsc, n1, n2);
  hipLaunchKernelGGL(k_tern, dim3((n1 + 255) / 256), dim3(256), 0, stream, in_proj, n1, wsc, 0, wq1);
  hipLaunchKernelGGL(k_tern, dim3((n2 + 255) / 256), dim3(256), 0, stream, out_proj, n2, wsc, 1, wq2);
  hipLaunchKernelGGL(k_normquant<DM>, dim3(TOKS), dim3(256), 0, stream, hidden, norm_w, q1, rs1);
  hipLaunchKernelGGL(k_gemm_mfma, dim3(TOKS / 128, (DIP + 127) / 128), dim3(256), 0, stream,
                     q1, wq1, rs1, (const float*)nullptr, zx, TOKS, DIP, DM);
  hipLaunchKernelGGL(k_conv, dim3(CVD / 256, TOKS), dim3(256), 0, stream, zx, conv_w, conv_b, sx,
                     bh2, bl2, ch2, cl2);
  hipLaunchKernelGGL(k_cumsum, dim3(512), dim3(256), 0, stream, zx, dt_bias, A_log, dtv, acs, csum);
  hipLaunchKernelGGL(k_gram, dim3(128), dim3(256), 0, stream, bh2, bl2, ch2, cl2, gr2);
  hipLaunchKernelGGL(k_prepuT, dim3(512), dim3(256), 0, stream, sx, dtv, uth2, utl2);
  hipLaunchKernelGGL(k_states2, dim3(512), dim3(256), 0, stream, sx, dtv, acs, csum, st);
  hipLaunchKernelGGL(k_chunkscan, dim3(2 * NH * HD * DST / 256), dim3(256), 0, stream, st, csum, ph2, pl2);
  hipLaunchKernelGGL(k_y11, dim3(2048), dim3(128), 0, stream, sx, acs, ch2, cl2, ph2, pl2, gr2, uth2, utl2, zx, Dp, yg);
  hipLaunchKernelGGL(k_normquant<DI>, dim3(TOKS), dim3(256), 0, stream, yg, out_norm, q2, rs2);
  hipLaunchKernelGGL(k_gemm_mfma, dim3(TOKS / 128, DM / 128), dim3(256), 0, stream,
                     q2, wq2, rs2, hidden, out, TOKS, DM, DI);
  (void)in_sizes; (void)n_in; (void)out_size; (void)ws_size;
}

// Round 15
// 353.758 us; speedup vs baseline: 1.1454x; 1.1078x over previous
//
#include <hip/hip_runtime.h>
#include <stdint.h>
#include <stddef.h>
#include <math.h>

#define TOKS 4096
#define DM   1024
#define DIP  4384
#define DI   2048
#define CVD  2304
#define NH   32
#define HD   64
#define DST  128
#define NCH  8
#define CHK  256

typedef int v4i  __attribute__((ext_vector_type(4)));
typedef int v16i __attribute__((ext_vector_type(16)));
typedef short s8v __attribute__((ext_vector_type(8)));
typedef float f16v __attribute__((ext_vector_type(16)));
typedef unsigned short ushort_t;

// ---------------- ws layout (bytes) ----------------
static const size_t OFF_ZX    = 0;                               // float TOKS*DIP
static const size_t OFF_SX    = OFF_ZX + (size_t)TOKS*DIP*4;     // float TOKS*CVD
static const size_t OFF_ST    = OFF_SX + (size_t)TOKS*CVD*4;     // float 512*HD*DST
static const size_t OFF_YG    = OFF_ST + (size_t)512*HD*DST*4;   // float TOKS*DI
static const size_t OFF_Q1    = OFF_YG + (size_t)TOKS*DI*4;      // i8 TOKS*DM
static const size_t OFF_Q2    = OFF_Q1 + (size_t)TOKS*DM;        // i8 TOKS*DI
static const size_t OFF_WQ1   = OFF_Q2 + (size_t)TOKS*DI;        // i8 DIP*DM
static const size_t OFF_WQ2   = OFF_WQ1 + (size_t)DIP*DM;        // i8 DM*DI
static const size_t OFF_RS1   = OFF_WQ2 + (size_t)DM*DI;         // float TOKS
static const size_t OFF_RS2   = OFF_RS1 + (size_t)TOKS*4;        // float TOKS
static const size_t OFF_DT    = OFF_RS2 + (size_t)TOKS*4;        // float TOKS*NH
static const size_t OFF_ACS   = OFF_DT + (size_t)TOKS*NH*4;      // double 512*CHK
static const size_t OFF_CSUM  = OFF_ACS + (size_t)512*CHK*8;     // double 512
static const size_t OFF_PART  = OFF_CSUM + 512*8;                // double 1024
static const size_t OFF_WSC   = OFF_PART + 1024*8;               // double 2
static const size_t OFF_BH    = OFF_WSC + 64;                    // ushort TOKS*128 (frag-major)
static const size_t OFF_BL    = OFF_BH  + (size_t)TOKS*128*2;
static const size_t OFF_CHG   = OFF_BL  + (size_t)TOKS*128*2;    // ushort TOKS*128 (frag-major)
static const size_t OFF_CLG   = OFF_CHG + (size_t)TOKS*128*2;
static const size_t OFF_GRAM  = OFF_CLG + (size_t)TOKS*128*2;    // float 16*256*256 (frag-major)
static const size_t OFF_UTH   = OFF_GRAM + (size_t)16*256*256*4; // ushort 512*64*256 (frag-major)
static const size_t OFF_UTL   = OFF_UTH + (size_t)512*64*256*2;
static const size_t OFF_PH    = OFF_UTL + (size_t)512*64*256*2;  // ushort 512*64*128 (frag-major)
static const size_t OFF_PL    = OFF_PH  + (size_t)512*64*128*2;
static const size_t OFF_BTH   = OFF_PL + (size_t)512*64*128*2;   // ushort 16*4*16*2*32*8 (B^T frag-major)
static const size_t OFF_BTL   = OFF_BTH + (size_t)16*4*16*2*32*8*2;

// ---------------- bf16 split helpers ----------------
__device__ __forceinline__ ushort_t f2bf(float x) {
  union { float f; unsigned int u; } v; v.f = x;
  unsigned int r = v.u + 0x7FFFu + ((v.u >> 16) & 1u);
  return (ushort_t)(r >> 16);
}
__device__ __forceinline__ float bf2f(ushort_t h) {
  union { unsigned int u; float f; } v; v.u = ((unsigned int)h) << 16;
  return v.f;
}

// ---------------- block reduction helpers (blockDim = 256) ----------------
__device__ __forceinline__ double bsumd(double v, double* sb) {
#pragma unroll
  for (int o = 32; o; o >>= 1) v += __shfl_down(v, o);
  int lane = threadIdx.x & 63, w = threadIdx.x >> 6;
  __syncthreads();
  if (lane == 0) sb[w] = v;
  __syncthreads();
  return sb[0] + sb[1] + sb[2] + sb[3];
}
__device__ __forceinline__ double bmaxd(double v, double* sb) {
#pragma unroll
  for (int o = 32; o; o >>= 1) v = fmax(v, __shfl_down(v, o));
  int lane = threadIdx.x & 63, w = threadIdx.x >> 6;
  __syncthreads();
  if (lane == 0) sb[w] = v;
  __syncthreads();
  return fmax(fmax(sb[0], sb[1]), fmax(sb[2], sb[3]));
}
__device__ __forceinline__ void bsum3d(double& a, double& b, double& c, double* sb) {
#pragma unroll
  for (int o = 32; o; o >>= 1) {
    a += __shfl_down(a, o);
    b += __shfl_down(b, o);
    c += __shfl_down(c, o);
  }
  int lane = threadIdx.x & 63, w = threadIdx.x >> 6;
  __syncthreads();
  if (lane == 0) { sb[w * 3 + 0] = a; sb[w * 3 + 1] = b; sb[w * 3 + 2] = c; }
  __syncthreads();
  a = sb[0] + sb[3] + sb[6] + sb[9];
  b = sb[1] + sb[4] + sb[7] + sb[10];
  c = sb[2] + sb[5] + sb[8] + sb[11];
}

// ---------------- weight scale (mean |w|), fp64 ----------------
__global__ void __launch_bounds__(256) k_absmean(const float* __restrict__ w, int n, double* __restrict__ part) {
  double s = 0.0;
  for (int i = blockIdx.x * 256 + threadIdx.x; i < n; i += 512 * 256) s += (double)fabsf(w[i]);
  __shared__ double sb[4];
  s = bsumd(s, sb);
  if (threadIdx.x == 0) part[blockIdx.x] = s;
}

__global__ void __launch_bounds__(256) k_wscale(const double* __restrict__ part, double* __restrict__ wsc, int n1, int n2) {
  __shared__ double sb[4];
  double s = part[threadIdx.x] + part[threadIdx.x + 256];
  double t1 = bsumd(s, sb);
  __syncthreads();
  s = part[512 + threadIdx.x] + part[512 + threadIdx.x + 256];
  double t2 = bsumd(s, sb);
  if (threadIdx.x == 0) {
    wsc[0] = fmax(t1 / (double)n1, 1e-5);
    wsc[1] = fmax(t2 / (double)n2, 1e-5);
  }
}

__global__ void __launch_bounds__(256) k_tern(const float* __restrict__ w, int n, const double* __restrict__ wsc, int which, int8_t* __restrict__ out) {
  int i = blockIdx.x * 256 + threadIdx.x;
  if (i < n) {
    double sc = wsc[which];
    double q = fmin(fmax(rint((double)w[i] / sc), -1.0), 1.0);
    out[i] = (int8_t)q;
  }
}

// ---------------- rmsnorm + layernorm + activation quant (fp64 decisions, fused reductions) ----------------
template <int D>
__global__ void __launch_bounds__(256) k_normquant(const float* __restrict__ in, const float* __restrict__ w,
                                                   int8_t* __restrict__ q, float* __restrict__ rs) {
  constexpr int E = D / 256;
  int t = blockIdx.x, tid = threadIdx.x;
  const float* row = in + (size_t)t * D;
  __shared__ double sb[12];
  double y[E];
  double s0 = 0.0, s1 = 0.0, s2 = 0.0;
#pragma unroll
  for (int i = 0; i < E; i++) {
    double xv = (double)row[tid + 256 * i];
    double wv = (double)w[tid + 256 * i];
    s0 += xv * xv;
    double yy = wv * xv;
    y[i] = yy;
    s1 += yy;
    s2 += yy * yy;
  }
  bsum3d(s0, s1, s2, sb);
  double rr = 1.0 / sqrt(s0 / (double)D + 1e-6);
  double mu = rr * (s1 / (double)D);
  double var = rr * rr * (s2 / (double)D) - mu * mu;
  double rv = 1.0 / sqrt(var + 1e-5);
  double M = 0.0;
#pragma unroll
  for (int i = 0; i < E; i++) { y[i] = y[i] * rr - mu; M = fmax(M, fabs(y[i])); }
  M = bmaxd(M, sb);
  double am = fmax(M * rv, 1e-5);
  double sc = 127.0 / am;
#pragma unroll
  for (int i = 0; i < E; i++) {
    double qq = fmin(fmax(rint(y[i] * rv * sc), -128.0), 127.0);
    q[(size_t)t * D + tid + 256 * i] = (int8_t)qq;
  }
  if (tid == 0) rs[t] = (float)(am / 127.0);
}

// ---------------- int8 x ternary GEMM via MFMA i8 ----------------
__global__ void __launch_bounds__(256, 3) k_gemm_mfma(const int8_t* __restrict__ A, const int8_t* __restrict__ W,
                                                      const float* __restrict__ rs, const float* __restrict__ addend,
                                                      float* __restrict__ out, int M, int N, int K) {
  __shared__ int8_t Al[128 * 80];
  __shared__ int8_t Bl[128 * 80];
  int m0 = blockIdx.x * 128, n0 = blockIdx.y * 128;
  int t = threadIdx.x;
  int w = t >> 6, lane = t & 63;
  int wm = w >> 1, wn = w & 1;
  int l31 = lane & 31, lh = lane >> 5;

  v16i acc[2][2] = {};

  for (int k0 = 0; k0 < K; k0 += 64) {
    __syncthreads();
#pragma unroll
    for (int it = 0; it < 2; ++it) {
      int c = t + 256 * it;
      int row = c >> 2, kc = (c & 3) * 16;
      int4 av = *(const int4*)(A + (size_t)(m0 + row) * K + k0 + kc);
      *(int4*)(Al + row * 80 + kc) = av;
      int4 bv;
      if (n0 + row < N) bv = *(const int4*)(W + (size_t)(n0 + row) * K + k0 + kc);
      else { bv.x = bv.y = bv.z = bv.w = 0; }
      *(int4*)(Bl + row * 80 + kc) = bv;
    }
    __syncthreads();
#pragma unroll
    for (int ks = 0; ks < 2; ++ks) {
      v4i af[2], bf[2];
#pragma unroll
      for (int tm = 0; tm < 2; ++tm)
        af[tm] = *(const v4i*)(Al + (wm * 64 + tm * 32 + l31) * 80 + ks * 32 + lh * 16);
#pragma unroll
      for (int tn = 0; tn < 2; ++tn)
        bf[tn] = *(const v4i*)(Bl + (wn * 64 + tn * 32 + l31) * 80 + ks * 32 + lh * 16);
#pragma unroll
      for (int tm = 0; tm < 2; ++tm)
#pragma unroll
        for (int tn = 0; tn < 2; ++tn)
          acc[tm][tn] = __builtin_amdgcn_mfma_i32_32x32x32_i8(af[tm], bf[tn], acc[tm][tn], 0, 0, 0);
    }
  }

#pragma unroll
  for (int tm = 0; tm < 2; ++tm)
#pragma unroll
    for (int tn = 0; tn < 2; ++tn) {
      int n = n0 + wn * 64 + tn * 32 + l31;
      if (n < N) {
#pragma unroll
        for (int r = 0; r < 16; ++r) {
          int mrel = (r & 3) + 8 * (r >> 2) + 4 * lh;
          int m = m0 + wm * 64 + tm * 32 + mrel;
          float v = rs[m] * (float)acc[tm][tn][r];
          if (addend) v += addend[(size_t)m * N + n];
          out[(size_t)m * N + n] = v;
        }
      }
    }
}

// ---------------- depthwise causal conv(4) + SiLU, fused frag-major B/C bf16 split + B^T frags ----------------
__global__ void __launch_bounds__(256) k_conv(const float* __restrict__ zx, const float* __restrict__ cw,
                                              const float* __restrict__ cb, float* __restrict__ sx,
                                              ushort_t* __restrict__ bh2, ushort_t* __restrict__ bl2,
                                              ushort_t* __restrict__ ch2, ushort_t* __restrict__ cl2,
                                              ushort_t* __restrict__ bth, ushort_t* __restrict__ btl) {
  int c = blockIdx.x * 256 + threadIdx.x;
  int t = blockIdx.y;
  int b = t >> 11, l = t & 2047;
  float acc = cb[c];
#pragma unroll
  for (int k = 0; k < 4; k++) {
    int li = l - 3 + k;
    if (li >= 0) acc = fmaf(zx[(size_t)(b * 2048 + li) * DIP + DI + c], cw[c * 4 + k], acc);
  }
  float val = acc / (1.f + expf(-acc));
  sx[(size_t)t * CVD + c] = val;
  if (c >= DI) {
    int idx = c - DI;     // 0..255
    ushort_t hh = f2bf(val);
    ushort_t ll = f2bf(val - bf2f(hh));
    int bc = t >> 8, lt = (t >> 5) & 7, l31 = t & 31;
    int n = idx & 127;
    int ks = n >> 4, lhf = (n >> 3) & 1, j = n & 7;
    size_t o = ((((size_t)(bc * 8 + lt) * 8 + ks) * 2 + lhf) * 32 + l31) * 8 + j;
    if (idx < 128) {
      bh2[o] = hh; bl2[o] = ll;
      // B^T frags for states GEMM: lane = n, k = s
      int s = t & 255;
      int nt = n >> 5, n31 = n & 31;
      int kg = s >> 4, lhf2 = (s >> 3) & 1, j2 = s & 7;
      size_t o2 = ((((size_t)(bc * 4 + nt) * 16 + kg) * 2 + lhf2) * 32 + n31) * 8 + j2;
      bth[o2] = hh; btl[o2] = ll;
    } else {
      ch2[o] = hh; cl2[o] = ll;
    }
  }
}

// ---------------- dt + per-(b,c,h) cumsum of a = dt * (-exp(A_log)), in fp64 ----------------
__global__ void __launch_bounds__(256) k_cumsum(const float* __restrict__ zx, const float* __restrict__ dt_bias,
                                                const float* __restrict__ A_log, float* __restrict__ dtv,
                                                double* __restrict__ acs, double* __restrict__ csum) {
  int bid = blockIdx.x;
  int h = bid & 31, bc = bid >> 5;
  int s = threadIdx.x;
  int tok = bc * 256 + s;
  float x = zx[(size_t)tok * DIP + (DI + CVD) + h] + dt_bias[h];
  float dt = fmaxf(x, 0.f) + log1pf(expf(-fabsf(x)));
  dtv[(size_t)tok * 32 + h] = dt;
  double negA = -exp((double)A_log[h]);
  double a = (double)dt * negA;
  __shared__ double buf[256];
  buf[s] = a;
  __syncthreads();
  for (int o = 1; o < 256; o <<= 1) {
    double add = (s >= o) ? buf[s - o] : 0.0;
    __syncthreads();
    buf[s] += add;
    __syncthreads();
  }
  acs[(size_t)bid * 256 + s] = buf[s];
  if (s == 255) csum[bid] = buf[s];
}

// ---------------- Gram (frag-major in & out) ----------------
__global__ void __launch_bounds__(256) k_gram(const ushort_t* __restrict__ bh2, const ushort_t* __restrict__ bl2,
                                              const ushort_t* __restrict__ ch2, const ushort_t* __restrict__ cl2,
                                              float* __restrict__ gr2) {
  int blk = blockIdx.x;          // bc*8 + lt
  int bc = blk >> 3, lt = blk & 7;
  int t = threadIdx.x;
  int w = t >> 6, lane = t & 63;
  int l31 = lane & 31, lhf = lane >> 5;
  __shared__ float Gl[4][32 * 36];

  s8v ch[8], cl[8];
#pragma unroll
  for (int ks = 0; ks < 8; ++ks) {
    size_t ca = ((((size_t)(bc * 8 + lt) * 8 + ks) * 2 + lhf) * 32 + l31) * 8;
    ch[ks] = *(const s8v*)(ch2 + ca);
    cl[ks] = *(const s8v*)(cl2 + ca);
  }
  for (int st = w; st <= lt; st += 4) {
    f16v acc = {};
#pragma unroll
    for (int ks = 0; ks < 8; ++ks) {
      size_t ba = ((((size_t)(bc * 8 + st) * 8 + ks) * 2 + lhf) * 32 + l31) * 8;
      s8v bh = *(const s8v*)(bh2 + ba);
      s8v bl = *(const s8v*)(bl2 + ba);
      acc = __builtin_amdgcn_mfma_f32_32x32x16_bf16(ch[ks], bh, acc, 0, 0, 0);
      acc = __builtin_amdgcn_mfma_f32_32x32x16_bf16(ch[ks], bl, acc, 0, 0, 0);
      acc = __builtin_amdgcn_mfma_f32_32x32x16_bf16(cl[ks], bh, acc, 0, 0, 0);
    }
#pragma unroll
    for (int rr = 0; rr < 16; ++rr) {
      int lrow = (rr & 3) + 8 * (rr >> 2) + 4 * lhf;
      Gl[w][lrow * 36 + l31] = acc[rr];
    }
#pragma unroll
    for (int i2 = 0; i2 < 2; ++i2) {
      int idx = i2 * 2 + lhf;
      int k2g = idx >> 1, lhf2 = idx & 1;
      size_t gb = ((((size_t)(bc * 8 + lt) * 8 + st) * 2 + k2g) * 2 + lhf2) * 256 + l31 * 8;
      float4 a = *(const float4*)(&Gl[w][l31 * 36 + k2g * 16 + lhf2 * 8]);
      float4 b = *(const float4*)(&Gl[w][l31 * 36 + k2g * 16 + lhf2 * 8 + 4]);
      *(float4*)(gr2 + gb) = a;
      *(float4*)(gr2 + gb + 4) = b;
    }
  }
}

// ---------------- uT precompute (frag-major out) ----------------
__global__ void __launch_bounds__(256) k_prepuT(const float* __restrict__ sx, const float* __restrict__ dtv,
                                                ushort_t* __restrict__ uth2, ushort_t* __restrict__ utl2) {
  int r = blockIdx.x;           // (b*8+c)*32+h
  int h = r & 31, bc = r >> 5;
  int t = threadIdx.x;
  __shared__ float Xs[64 * 68];
  __shared__ float dts[64];
  for (int slab = 0; slab < 4; ++slab) {
    int s0 = slab * 64;
    if (slab) __syncthreads();
    if (t < 64) dts[t] = dtv[(size_t)(bc * 256 + s0 + t) * 32 + h];
    {
      int s = t >> 2, pg = (t & 3) * 16;
      const float* xr = sx + (size_t)(bc * 256 + s0 + s) * CVD + h * 64 + pg;
      float* dst = &Xs[s * 68 + pg];
#pragma unroll
      for (int i = 0; i < 4; ++i)
        *(float4*)(dst + i * 4) = *(const float4*)(xr + i * 4);
    }
    __syncthreads();
#pragma unroll
    for (int half = 0; half < 2; ++half) {
      int it = t + half * 256;
      int l31 = it & 31, g = it >> 5;    // g 0..15
      int stl = g >> 3, k2 = (g >> 2) & 1, pt = (g >> 1) & 1, lhf = g & 1;
      int p = pt * 32 + l31;
      int sb = stl * 32 + k2 * 16 + lhf * 8;   // within slab
      union { int4 q; ushort_t e[8]; } H, L;
#pragma unroll
      for (int j = 0; j < 8; ++j) {
        float f = Xs[(sb + j) * 68 + p] * dts[sb + j];
        ushort_t hh = f2bf(f);
        H.e[j] = hh;
        L.e[j] = f2bf(f - bf2f(hh));
      }
      int st = slab * 2 + stl;
      size_t base = (((((size_t)r * 8 + st) * 2 + k2) * 2 + pt) * 2 + lhf) * 256 + l31 * 8;
      *(int4*)(uth2 + base) = H.q;
      *(int4*)(utl2 + base) = L.q;
    }
  }
}

// ---------------- per-chunk states via MFMA: states[p][n] = sum_s (x*dt)[s,p] * (decay*B)[s,n] ----------------
__global__ void __launch_bounds__(256) k_states3(const ushort_t* __restrict__ uth2, const ushort_t* __restrict__ utl2,
                                                 const ushort_t* __restrict__ bth, const ushort_t* __restrict__ btl,
                                                 const double* __restrict__ acs, const double* __restrict__ csum,
                                                 float* __restrict__ states) {
  int r = blockIdx.x;            // (b*8+c)*32+h
  int bc = r >> 5;
  int t = threadIdx.x, w = t >> 6, lane = t & 63;
  int n31 = lane & 31, lhf = lane >> 5;
  int pt = w & 1, nt0 = w >> 1;  // wave handles (pt, nt0) and (pt, nt0+2)
  __shared__ float wd[256];
  {
    double last = csum[r];
    wd[t] = expf((float)(last - acs[(size_t)r * 256 + t]));
  }
  __syncthreads();

  f16v acc0 = {}, acc1 = {};
  for (int kg = 0; kg < 16; ++kg) {
    int st = kg >> 1, k2 = kg & 1;
    size_t ua = (((((size_t)r * 8 + st) * 2 + k2) * 2 + pt) * 2 + lhf) * 256 + n31 * 8;
    s8v ah = *(const s8v*)(uth2 + ua);
    s8v al = *(const s8v*)(utl2 + ua);
#pragma unroll
    for (int half = 0; half < 2; ++half) {
      int nt = nt0 + half * 2;
      size_t ba = ((((size_t)(bc * 4 + nt) * 16 + kg) * 2 + lhf) * 32 + n31) * 8;
      s8v bh = *(const s8v*)(bth + ba);
      s8v bl = *(const s8v*)(btl + ba);
      union { s8v v; ushort_t e[8]; } BH, BL;
#pragma unroll
      for (int j = 0; j < 8; ++j) {
        int s = kg * 16 + lhf * 8 + j;
        float bv = (bf2f((ushort_t)bh[j]) + bf2f((ushort_t)bl[j])) * wd[s];
        ushort_t hh = f2bf(bv);
        BH.e[j] = hh;
        BL.e[j] = f2bf(bv - bf2f(hh));
      }
      if (half == 0) {
        acc0 = __builtin_amdgcn_mfma_f32_32x32x16_bf16(ah, BH.v, acc0, 0, 0, 0);
        acc0 = __builtin_amdgcn_mfma_f32_32x32x16_bf16(ah, BL.v, acc0, 0, 0, 0);
        acc0 = __builtin_amdgcn_mfma_f32_32x32x16_bf16(al, BH.v, acc0, 0, 0, 0);
      } else {
        acc1 = __builtin_amdgcn_mfma_f32_32x32x16_bf16(ah, BH.v, acc1, 0, 0, 0);
        acc1 = __builtin_amdgcn_mfma_f32_32x32x16_bf16(ah, BL.v, acc1, 0, 0, 0);
        acc1 = __builtin_amdgcn_mfma_f32_32x32x16_bf16(al, BH.v, acc1, 0, 0, 0);
      }
    }
  }
  size_t base = (size_t)r * (HD * DST);
#pragma unroll
  for (int rr = 0; rr < 16; ++rr) {
    int prel = (rr & 3) + 8 * (rr >> 2) + 4 * lhf;
    int p = pt * 32 + prel;
    states[base + (size_t)p * DST + nt0 * 32 + n31] = acc0[rr];
    states[base + (size_t)p * DST + (nt0 + 2) * 32 + n31] = acc1[rr];
  }
}

// ---------------- chunk-state recurrence; emits prev as frag-major bf16 hi/lo ----------------
__global__ void __launch_bounds__(256) k_chunkscan(float* __restrict__ states, const double* __restrict__ csum,
                                                   ushort_t* __restrict__ ph2, ushort_t* __restrict__ pl2) {
  int idx = blockIdx.x * 256 + threadIdx.x;
  int n = idx & 127, p = (idx >> 7) & 63, h = (idx >> 13) & 31, b = idx >> 18;
  int ks = n >> 4, lhf = (n >> 3) & 1, j = n & 7, pt = p >> 5, l31 = p & 31;
  float Nv = 0.f;
  for (int c = 0; c < 8; c++) {
    int bid = (b * 8 + c) * 32 + h;
    size_t addr = (size_t)bid * (HD * DST) + p * DST + n;
    float s = states[addr];
    states[addr] = Nv;
    ushort_t hh = f2bf(Nv);
    size_t o = (((((size_t)bid * 8 + ks) * 2 + pt) * 2 + lhf) * 32 + l31) * 8 + j;
    ph2[o] = hh;
    pl2[o] = f2bf(Nv - bf2f(hh));
    Nv = Nv * expf((float)csum[bid]) + s;
  }
}

// ---------------- fused Y: single-wave blocks, coalesced frag-major loads (round-12 k_y9) ----------------
__global__ void __launch_bounds__(64) k_y9(const float* __restrict__ sx, const double* __restrict__ acs,
                                           const ushort_t* __restrict__ ch2, const ushort_t* __restrict__ cl2,
                                           const ushort_t* __restrict__ ph2, const ushort_t* __restrict__ pl2,
                                           const float* __restrict__ gr2,
                                           const ushort_t* __restrict__ uth2, const ushort_t* __restrict__ utl2,
                                           const float* __restrict__ zx, const float* __restrict__ Dp,
                                           float* __restrict__ yg) {
  int myid = (blockIdx.x & 7) * 512 + (blockIdx.x >> 3);
  int r = myid >> 3, lt = myid & 7;      // r = (b*8+c)*32+h
  int h = r & 31, bc = r >> 5;
  int lane = threadIdx.x;                // 0..63
  int l31 = lane & 31, lhf = lane >> 5;
  int lw = lt * 32;
  int lg = lw + l31;
  const double* acsr = acs + (size_t)r * 256;
  double a_l = acsr[lg];

  // ---- Y_off: Yacc = C · prev^T ----
  f16v Yacc[2] = {};
#pragma unroll
  for (int ks = 0; ks < 8; ++ks) {
    size_t ca = ((((size_t)(bc * 8 + lt) * 8 + ks) * 2 + lhf) * 32 + l31) * 8;
    s8v ch = *(const s8v*)(ch2 + ca);
    s8v cl = *(const s8v*)(cl2 + ca);
#pragma unroll
    for (int pt = 0; pt < 2; ++pt) {
      size_t pa = (((((size_t)r * 8 + ks) * 2 + pt) * 2 + lhf) * 32 + l31) * 8;
      s8v ph = *(const s8v*)(ph2 + pa);
      s8v pl = *(const s8v*)(pl2 + pa);
      Yacc[pt] = __builtin_amdgcn_mfma_f32_32x32x16_bf16(ch, ph, Yacc[pt], 0, 0, 0);
      Yacc[pt] = __builtin_amdgcn_mfma_f32_32x32x16_bf16(ch, pl, Yacc[pt], 0, 0, 0);
      Yacc[pt] = __builtin_amdgcn_mfma_f32_32x32x16_bf16(cl, ph, Yacc[pt], 0, 0, 0);
    }
  }
#pragma unroll
  for (int rr = 0; rr < 16; ++rr) {
    int lrow = (rr & 3) + 8 * (rr >> 2) + 4 * lhf;
    float el = expf((float)acsr[lw + lrow]);
    Yacc[0][rr] *= el;
    Yacc[1][rr] *= el;
  }

  // ---- main loop over 32-wide s subtiles ----
  for (int st = 0; st <= lt; ++st) {
#pragma unroll
    for (int k2 = 0; k2 < 2; ++k2) {
      size_t gb = (((((size_t)(bc * 8 + lt) * 8 + st) * 2 + k2) * 2 + lhf) * 256) + l31 * 8;
      float4 g0 = *(const float4*)(gr2 + gb);
      float4 g1 = *(const float4*)(gr2 + gb + 4);
      float gv[8] = {g0.x, g0.y, g0.z, g0.w, g1.x, g1.y, g1.z, g1.w};
      int sbase = st * 32 + k2 * 16 + lhf * 8;
      union { s8v v; ushort_t e[8]; } AH, AL;
#pragma unroll
      for (int j = 0; j < 8; ++j) {
        float v = 0.f;
        if (sbase + j <= lg) v = expf((float)(a_l - acsr[sbase + j])) * gv[j];
        ushort_t hh = f2bf(v);
        AH.e[j] = hh;
        AL.e[j] = f2bf(v - bf2f(hh));
      }
#pragma unroll
      for (int pt = 0; pt < 2; ++pt) {
        size_t ub = ((((((size_t)r * 8 + st) * 2 + k2) * 2 + pt) * 2 + lhf) * 256) + l31 * 8;
        s8v uh = *(const s8v*)(uth2 + ub);
        s8v ul = *(const s8v*)(utl2 + ub);
        Yacc[pt] = __builtin_amdgcn_mfma_f32_32x32x16_bf16(AH.v, uh, Yacc[pt], 0, 0, 0);
        Yacc[pt] = __builtin_amdgcn_mfma_f32_32x32x16_bf16(AH.v, ul, Yacc[pt], 0, 0, 0);
        Yacc[pt] = __builtin_amdgcn_mfma_f32_32x32x16_bf16(AL.v, uh, Yacc[pt], 0, 0, 0);
      }
    }
  }

  // ---- epilogue: + x*Dp, gate silu(z), store ----
  float dph = Dp[h];
#pragma unroll
  for (int pt = 0; pt < 2; ++pt) {
    int p = pt * 32 + l31;
#pragma unroll
    for (int rr = 0; rr < 16; ++rr) {
      int lrow = (rr & 3) + 8 * (rr >> 2) + 4 * lhf;
      size_t tok = (size_t)(bc * 256 + lw + lrow);
      float xv = sx[tok * CVD + h * 64 + p];
      float zv = zx[tok * DIP + h * 64 + p];
      float y = (Yacc[pt][rr] + xv * dph) * (zv / (1.f + expf(-zv)));
      yg[tok * DI + h * 64 + p] = y;
    }
  }
}

// ---------------- launch ----------------
extern "C" void kernel_launch(void* const* d_in, const int* in_sizes, int n_in,
                              void* d_out, int out_size, void* d_ws, size_t ws_size,
                              hipStream_t stream) {
  const float* hidden   = (const float*)d_in[0];
  const float* norm_w   = (const float*)d_in[1];
  const float* in_proj  = (const float*)d_in[2];
  const float* conv_w   = (const float*)d_in[3];
  const float* conv_b   = (const float*)d_in[4];
  const float* A_log    = (const float*)d_in[5];
  const float* Dp       = (const float*)d_in[6];
  const float* dt_bias  = (const float*)d_in[7];
  const float* out_norm = (const float*)d_in[8];
  const float* out_proj = (const float*)d_in[9];
  float* out = (float*)d_out;

  char* ws = (char*)d_ws;
  float*  zx    = (float*)(ws + OFF_ZX);
  float*  sx    = (float*)(ws + OFF_SX);
  float*  st    = (float*)(ws + OFF_ST);
  float*  yg    = (float*)(ws + OFF_YG);
  int8_t* q1    = (int8_t*)(ws + OFF_Q1);
  int8_t* q2    = (int8_t*)(ws + OFF_Q2);
  int8_t* wq1   = (int8_t*)(ws + OFF_WQ1);
  int8_t* wq2   = (int8_t*)(ws + OFF_WQ2);
  float*  rs1   = (float*)(ws + OFF_RS1);
  float*  rs2   = (float*)(ws + OFF_RS2);
  float*  dtv   = (float*)(ws + OFF_DT);
  double* acs   = (double*)(ws + OFF_ACS);
  double* csum  = (double*)(ws + OFF_CSUM);
  double* part  = (double*)(ws + OFF_PART);
  double* wsc   = (double*)(ws + OFF_WSC);
  ushort_t* bh2 = (ushort_t*)(ws + OFF_BH);
  ushort_t* bl2 = (ushort_t*)(ws + OFF_BL);
  ushort_t* ch2 = (ushort_t*)(ws + OFF_CHG);
  ushort_t* cl2 = (ushort_t*)(ws + OFF_CLG);
  float*  gr2   = (float*)(ws + OFF_GRAM);
  ushort_t* uth2 = (ushort_t*)(ws + OFF_UTH);
  ushort_t* utl2 = (ushort_t*)(ws + OFF_UTL);
  ushort_t* ph2 = (ushort_t*)(ws + OFF_PH);
  ushort_t* pl2 = (ushort_t*)(ws + OFF_PL);
  ushort_t* bth = (ushort_t*)(ws + OFF_BTH);
  ushort_t* btl = (ushort_t*)(ws + OFF_BTL);

  const int n1 = DIP * DM, n2 = DM * DI;

  hipLaunchKernelGGL(k_absmean, dim3(512), dim3(256), 0, stream, in_proj, n1, part);
  hipLaunchKernelGGL(k_absmean, dim3(512), dim3(256), 0, stream, out_proj, n2, part + 512);
  hipLaunchKernelGGL(k_wscale, dim3(1), dim3(256), 0, stream, part, wsc, n1, n2);
  hipLaunchKernelGGL(k_tern, dim3((n1 + 255) / 256), dim3(256), 0, stream, in_proj, n1, wsc, 0, wq1);
  hipLaunchKernelGGL(k_tern, dim3((n2 + 255) / 256), dim3(256), 0, stream, out_proj, n2, wsc, 1, wq2);
  hipLaunchKernelGGL(k_normquant<DM>, dim3(TOKS), dim3(256), 0, stream, hidden, norm_w, q1, rs1);
  hipLaunchKernelGGL(k_gemm_mfma, dim3(TOKS / 128, (DIP + 127) / 128), dim3(256), 0, stream,
                     q1, wq1, rs1, (const float*)nullptr, zx, TOKS, DIP, DM);
  hipLaunchKernelGGL(k_conv, dim3(CVD / 256, TOKS), dim3(256), 0, stream, zx, conv_w, conv_b, sx,
                     bh2, bl2, ch2, cl2, bth, btl);
  hipLaunchKernelGGL(k_cumsum, dim3(512), dim3(256), 0, stream, zx, dt_bias, A_log, dtv, acs, csum);
  hipLaunchKernelGGL(k_gram, dim3(128), dim3(256), 0, stream, bh2, bl2, ch2, cl2, gr2);
  hipLaunchKernelGGL(k_prepuT, dim3(512), dim3(256), 0, stream, sx, dtv, uth2, utl2);
  hipLaunchKernelGGL(k_states3, dim3(512), dim3(256), 0, stream, uth2, utl2, bth, btl, acs, csum, st);
  hipLaunchKernelGGL(k_chunkscan, dim3(2 * NH * HD * DST / 256), dim3(256), 0, stream, st, csum, ph2, pl2);
  hipLaunchKernelGGL(k_y9, dim3(4096), dim3(64), 0, stream, sx, acs, ch2, cl2, ph2, pl2, gr2, uth2, utl2, zx, Dp, yg);
  hipLaunchKernelGGL(k_normquant<DI>, dim3(TOKS), dim3(256), 0, stream, yg, out_norm, q2, rs2);
  hipLaunchKernelGGL(k_gemm_mfma, dim3(TOKS / 128, DM / 128), dim3(256), 0, stream,
                     q2, wq2, rs2, hidden, out, TOKS, DM, DI);
  (void)in_sizes; (void)n_in; (void)out_size; (void)ws_size;
}